// Round 1
// baseline (672.183 us; speedup 1.0000x reference)
//
#include <hip/hip_runtime.h>

// Problem constants (fixed by setup_inputs)
constexpr int Bb = 4;
constexpr int Nn = 20000;
constexpr int Ff = 64;
constexpr int Hh = 128;
constexpr float BN_EPS = 1e-5f;

// ---------------------------------------------------------------------------
// K1: degree count over dst (self-loops added analytically later as +1)
__global__ void k_deg(const int* __restrict__ dst, int E, int* __restrict__ deg) {
    int e = blockIdx.x * blockDim.x + threadIdx.x;
    if (e < E) atomicAdd(&deg[dst[e]], 1);
}

// ---------------------------------------------------------------------------
// K2: single-block tiled exclusive scan over (deg[v]+1) -> rowptr, cursor, dinv
__global__ void k_scan(const int* __restrict__ deg, int* __restrict__ rowptr,
                       int* __restrict__ cursor, float* __restrict__ dinv) {
    __shared__ int tile[1024];
    __shared__ int carry_s;
    if (threadIdx.x == 0) carry_s = 0;
    __syncthreads();
    for (int base = 0; base < Nn; base += 1024) {
        const int i = base + (int)threadIdx.x;
        const int cnt = (i < Nn) ? (deg[i] + 1) : 0;  // +1 = self loop
        tile[threadIdx.x] = cnt;
        __syncthreads();
        // Hillis-Steele inclusive scan
        for (int offd = 1; offd < 1024; offd <<= 1) {
            int t = (threadIdx.x >= (unsigned)offd) ? tile[threadIdx.x - offd] : 0;
            __syncthreads();
            tile[threadIdx.x] += t;
            __syncthreads();
        }
        const int incl = tile[threadIdx.x];
        const int c = carry_s;
        __syncthreads();
        if (threadIdx.x == 1023) carry_s = c + incl;
        if (i < Nn) {
            const int excl = c + incl - cnt;
            rowptr[i] = excl;
            cursor[i] = excl;
            dinv[i]   = rsqrtf((float)cnt);  // deg>=1 always (self loop)
        }
        __syncthreads();
    }
    if (threadIdx.x == 0) rowptr[Nn] = carry_s;
}

// ---------------------------------------------------------------------------
// K3: fill CSR (incoming-edge lists per destination) + per-edge norm
__global__ void k_fill(const int* __restrict__ src, const int* __restrict__ dst, int E,
                       const float* __restrict__ dinv, int* __restrict__ cursor,
                       int* __restrict__ csr_src, float* __restrict__ csr_norm) {
    int t = blockIdx.x * blockDim.x + threadIdx.x;
    int s, d;
    if (t < E) { s = src[t]; d = dst[t]; }
    else if (t < E + Nn) { s = d = t - E; }
    else return;
    int pos = atomicAdd(&cursor[d], 1);
    csr_src[pos]  = s;
    csr_norm[pos] = dinv[s] * dinv[d];
}

// ---------------------------------------------------------------------------
// K4: GEMM  Y[rows,128] = (X*scale+shift)[rows,K] @ W[K,128]
// scale/shift == nullptr -> raw X (layer 1). 256 threads: c = tid&127 owns an
// output channel (W column held in VGPRs), g = tid>>7 picks row parity.
template <int K>
__global__ __launch_bounds__(256) void k_gemm(const float* __restrict__ X,
                                              const float* __restrict__ W,
                                              const float* __restrict__ scale,
                                              const float* __restrict__ shift,
                                              float* __restrict__ Y) {
    constexpr int R = 64;  // rows per block
    __shared__ float xs[R][K];
    const int c = threadIdx.x & (Hh - 1);
    const int g = threadIdx.x >> 7;
    float w[K];
#pragma unroll
    for (int k = 0; k < K; ++k) w[k] = W[k * Hh + c];

    const int row0 = blockIdx.x * R;
    // cooperative staging (fully coalesced: consecutive tid -> consecutive addr)
    for (int idx = threadIdx.x; idx < R * K; idx += 256) {
        float v = X[(size_t)row0 * K + idx];
        if (scale) { const int kk = idx & (K - 1); v = v * scale[kk] + shift[kk]; }
        xs[idx / K][idx & (K - 1)] = v;
    }
    __syncthreads();

    for (int r = g; r < R; r += 2) {
        float acc = 0.f;
#pragma unroll
        for (int k = 0; k < K; k += 4) {
            const float4 xv = *(const float4*)&xs[r][k];  // broadcast across lanes
            acc = fmaf(xv.x, w[k],     acc);
            acc = fmaf(xv.y, w[k + 1], acc);
            acc = fmaf(xv.z, w[k + 2], acc);
            acc = fmaf(xv.w, w[k + 3], acc);
        }
        Y[((size_t)(row0 + r)) * Hh + c] = acc;
    }
}

// ---------------------------------------------------------------------------
// K5: aggregation. One wave per node; lane owns channels (2*lane, 2*lane+1);
// all 4 batches per edge. Epilogue: +bias, ReLU, store, BN partial stats.
__global__ __launch_bounds__(256) void k_agg(const float* __restrict__ Hin,
                                             const int* __restrict__ rowptr,
                                             const int* __restrict__ csr_src,
                                             const float* __restrict__ csr_norm,
                                             const float* __restrict__ bias,
                                             float* __restrict__ Hout,
                                             float* __restrict__ gsum,
                                             float* __restrict__ gsq) {
    __shared__ float lsum[Hh], lsq[Hh];
    if (threadIdx.x < Hh) { lsum[threadIdx.x] = 0.f; lsq[threadIdx.x] = 0.f; }
    __syncthreads();

    const int wave = threadIdx.x >> 6;
    const int lane = threadIdx.x & 63;
    const int v = blockIdx.x * 4 + wave;
    const int c0 = lane * 2;

    if (v < Nn) {
        float a0[Bb], a1[Bb];
#pragma unroll
        for (int b = 0; b < Bb; ++b) { a0[b] = 0.f; a1[b] = 0.f; }
        const int beg = rowptr[v], end = rowptr[v + 1];
        for (int e = beg; e < end; ++e) {
            const int s = csr_src[e];
            const float nm = csr_norm[e];
#pragma unroll
            for (int b = 0; b < Bb; ++b) {
                const float2 hv = *(const float2*)(Hin + ((size_t)b * Nn + s) * Hh + c0);
                a0[b] = fmaf(nm, hv.x, a0[b]);
                a1[b] = fmaf(nm, hv.y, a1[b]);
            }
        }
        const float bias0 = bias[c0], bias1 = bias[c0 + 1];
        float t0 = 0.f, t1 = 0.f, q0 = 0.f, q1 = 0.f;
#pragma unroll
        for (int b = 0; b < Bb; ++b) {
            const float y0 = fmaxf(a0[b] + bias0, 0.f);
            const float y1 = fmaxf(a1[b] + bias1, 0.f);
            *(float2*)(Hout + ((size_t)b * Nn + v) * Hh + c0) = make_float2(y0, y1);
            t0 += y0; t1 += y1; q0 += y0 * y0; q1 += y1 * y1;
        }
        atomicAdd(&lsum[c0], t0);     atomicAdd(&lsum[c0 + 1], t1);
        atomicAdd(&lsq[c0],  q0);     atomicAdd(&lsq[c0 + 1],  q1);
    }
    __syncthreads();
    if (threadIdx.x < Hh) {
        atomicAdd(&gsum[threadIdx.x], lsum[threadIdx.x]);
        atomicAdd(&gsq[threadIdx.x],  lsq[threadIdx.x]);
    }
}

// ---------------------------------------------------------------------------
// K6: BN finalize -> per-channel scale/shift
__global__ void k_bnfin(const float* __restrict__ gsum, const float* __restrict__ gsq,
                        const float* __restrict__ gamma, const float* __restrict__ beta,
                        float* __restrict__ scale, float* __restrict__ shift) {
    const int c = threadIdx.x;
    const float inv = 1.0f / (float)(Bb * Nn);
    const float mu  = gsum[c] * inv;
    const float var = gsq[c] * inv - mu * mu;   // biased variance (torch BN fwd)
    const float sc  = gamma[c] * rsqrtf(var + BN_EPS);
    scale[c] = sc;
    shift[c] = beta[c] - mu * sc;
}

// ---------------------------------------------------------------------------
// K7: classifier: out[row] = sum_c (h*scale+shift)[c]*Wc[c] + bc. Wave per row.
__global__ __launch_bounds__(256) void k_cls(const float* __restrict__ Hin,
                                             const float* __restrict__ scale,
                                             const float* __restrict__ shift,
                                             const float* __restrict__ Wc,
                                             const float* __restrict__ bc,
                                             float* __restrict__ out) {
    const int wave = threadIdx.x >> 6;
    const int lane = threadIdx.x & 63;
    const size_t row = (size_t)blockIdx.x * 4 + wave;
    if (row >= (size_t)Bb * Nn) return;
    const int c0 = lane * 2;
    const float2 h = *(const float2*)(Hin + row * Hh + c0);
    float p = (h.x * scale[c0] + shift[c0]) * Wc[c0] +
              (h.y * scale[c0 + 1] + shift[c0 + 1]) * Wc[c0 + 1];
#pragma unroll
    for (int off = 32; off; off >>= 1) p += __shfl_down(p, off);
    if (lane == 0) out[row] = p + bc[0];
}

// ---------------------------------------------------------------------------
extern "C" void kernel_launch(void* const* d_in, const int* in_sizes, int n_in,
                              void* d_out, int out_size, void* d_ws, size_t ws_size,
                              hipStream_t stream) {
    const float* x      = (const float*)d_in[0];
    const int*   ei     = (const int*)d_in[1];
    const float* W1     = (const float*)d_in[2];
    const float* b1     = (const float*)d_in[3];
    const float* W2     = (const float*)d_in[4];
    const float* b2     = (const float*)d_in[5];
    const float* gamma1 = (const float*)d_in[6];
    const float* beta1  = (const float*)d_in[7];
    const float* gamma2 = (const float*)d_in[8];
    const float* beta2  = (const float*)d_in[9];
    const float* Wc     = (const float*)d_in[10];
    const float* bc     = (const float*)d_in[11];
    float* out = (float*)d_out;

    const int E = in_sizes[1] / 2;
    const int* src = ei;
    const int* dst = ei + E;

    char* ws = (char*)d_ws;
    size_t off = 0;
    auto alloc = [&](size_t bytes) -> char* {
        char* p = ws + off;
        off += (bytes + 255) & ~(size_t)255;
        return p;
    };
    int*   deg      = (int*)  alloc((size_t)Nn * 4);
    int*   cursor   = (int*)  alloc((size_t)Nn * 4);
    int*   rowptr   = (int*)  alloc((size_t)(Nn + 1) * 4);
    float* dinv     = (float*)alloc((size_t)Nn * 4);
    int*   csr_src  = (int*)  alloc((size_t)(E + Nn) * 4);
    float* csr_norm = (float*)alloc((size_t)(E + Nn) * 4);
    float* stats    = (float*)alloc((size_t)8 * Hh * 4);
    float* gsum1 = stats,          *gsq1 = stats + Hh;
    float* scale1 = stats + 2*Hh,  *shift1 = stats + 3*Hh;
    float* gsum2 = stats + 4*Hh,   *gsq2 = stats + 5*Hh;
    float* scale2 = stats + 6*Hh,  *shift2 = stats + 7*Hh;
    float* bufA = (float*)alloc((size_t)Bb * Nn * Hh * 4);
    float* bufB = (float*)alloc((size_t)Bb * Nn * Hh * 4);

    (void)hipMemsetAsync(deg, 0, (size_t)Nn * 4, stream);
    (void)hipMemsetAsync(gsum1, 0, (size_t)2 * Hh * 4, stream);
    (void)hipMemsetAsync(gsum2, 0, (size_t)2 * Hh * 4, stream);

    k_deg<<<(E + 255) / 256, 256, 0, stream>>>(dst, E, deg);
    k_scan<<<1, 1024, 0, stream>>>(deg, rowptr, cursor, dinv);
    k_fill<<<(E + Nn + 255) / 256, 256, 0, stream>>>(src, dst, E, dinv, cursor,
                                                     csr_src, csr_norm);

    // Layer 1
    k_gemm<Ff><<<(Bb * Nn) / 64, 256, 0, stream>>>(x, W1, nullptr, nullptr, bufA);
    k_agg<<<(Nn + 3) / 4, 256, 0, stream>>>(bufA, rowptr, csr_src, csr_norm, b1,
                                            bufB, gsum1, gsq1);
    k_bnfin<<<1, Hh, 0, stream>>>(gsum1, gsq1, gamma1, beta1, scale1, shift1);

    // Layer 2 (BN1 applied on GEMM input load)
    k_gemm<Hh><<<(Bb * Nn) / 64, 256, 0, stream>>>(bufB, W2, scale1, shift1, bufA);
    k_agg<<<(Nn + 3) / 4, 256, 0, stream>>>(bufA, rowptr, csr_src, csr_norm, b2,
                                            bufB, gsum2, gsq2);
    k_bnfin<<<1, Hh, 0, stream>>>(gsum2, gsq2, gamma2, beta2, scale2, shift2);

    // Classifier (BN2 applied inline)
    k_cls<<<(Bb * Nn + 3) / 4, 256, 0, stream>>>(bufB, scale2, shift2, Wc, bc, out);
}

// Round 2
// 493.503 us; speedup vs baseline: 1.3621x; 1.3621x over previous
//
#include <hip/hip_runtime.h>

// Problem constants (fixed by setup_inputs)
constexpr int Bb = 4;
constexpr int Nn = 20000;
constexpr int Ff = 64;
constexpr int Hh = 128;
constexpr float BN_EPS = 1e-5f;

// ---------------------------------------------------------------------------
// K1: degree count over dst (self-loops added analytically later as +1)
__global__ void k_deg(const int* __restrict__ dst, int E, int* __restrict__ deg) {
    int e = blockIdx.x * blockDim.x + threadIdx.x;
    if (e < E) atomicAdd(&deg[dst[e]], 1);
}

// ---------------------------------------------------------------------------
// K2: single-block tiled exclusive scan over (deg[v]+1) -> rowptr, cursor, dinv
__global__ void k_scan(const int* __restrict__ deg, int* __restrict__ rowptr,
                       int* __restrict__ cursor, float* __restrict__ dinv) {
    __shared__ int tile[1024];
    __shared__ int carry_s;
    if (threadIdx.x == 0) carry_s = 0;
    __syncthreads();
    for (int base = 0; base < Nn; base += 1024) {
        const int i = base + (int)threadIdx.x;
        const int cnt = (i < Nn) ? (deg[i] + 1) : 0;  // +1 = self loop
        tile[threadIdx.x] = cnt;
        __syncthreads();
        for (int offd = 1; offd < 1024; offd <<= 1) {
            int t = (threadIdx.x >= (unsigned)offd) ? tile[threadIdx.x - offd] : 0;
            __syncthreads();
            tile[threadIdx.x] += t;
            __syncthreads();
        }
        const int incl = tile[threadIdx.x];
        const int c = carry_s;
        __syncthreads();
        if (threadIdx.x == 1023) carry_s = c + incl;
        if (i < Nn) {
            const int excl = c + incl - cnt;
            rowptr[i] = excl;
            cursor[i] = excl;
            dinv[i]   = rsqrtf((float)cnt);
        }
        __syncthreads();
    }
    if (threadIdx.x == 0) rowptr[Nn] = carry_s;
}

// ---------------------------------------------------------------------------
// K3: fill CSR (incoming-edge lists per destination) + per-edge norm
__global__ void k_fill(const int* __restrict__ src, const int* __restrict__ dst, int E,
                       const float* __restrict__ dinv, int* __restrict__ cursor,
                       int* __restrict__ csr_src, float* __restrict__ csr_norm) {
    int t = blockIdx.x * blockDim.x + threadIdx.x;
    int s, d;
    if (t < E) { s = src[t]; d = dst[t]; }
    else if (t < E + Nn) { s = d = t - E; }
    else return;
    int pos = atomicAdd(&cursor[d], 1);
    csr_src[pos]  = s;
    csr_norm[pos] = dinv[s] * dinv[d];
}

// ---------------------------------------------------------------------------
// K4: GEMM  Y[rows,128] = (X*scale+shift)[rows,K] @ W[K,128]
// Register-tiled: 256 threads, block tile 64 rows x 128 cols, K-tiles of 32.
// Thread (tr=tid>>4, tc=tid&15) owns rows 4tr..4tr+3, cols {4tc..+3, 64+4tc..+3}
// -> acc[4][8]. Per k-step: 4x ds_read_b32 (2-way max) + 2x ds_read_b128
// (contiguous 256B rounds, 2-way) feeding 32 FMAs -> VALU-bound.
template <int K>
__global__ __launch_bounds__(256) void k_gemm(const float* __restrict__ X,
                                              const float* __restrict__ W,
                                              const float* __restrict__ scale,
                                              const float* __restrict__ shift,
                                              float* __restrict__ Y) {
    constexpr int KT = 32;
    constexpr int RS = KT + 4;            // xs row stride (pad 4: bank-spread, 16B aligned)
    __shared__ float sx[64 * RS];         // 9.2 KB
    __shared__ float sw[KT * Hh];         // 16 KB

    const int tid = threadIdx.x;
    const int tr = tid >> 4;              // 0..15
    const int tc = tid & 15;              // 0..15
    const int row0 = blockIdx.x * 64;

    float acc[4][8];
#pragma unroll
    for (int i = 0; i < 4; ++i)
#pragma unroll
        for (int j = 0; j < 8; ++j) acc[i][j] = 0.f;

    const int srow = tid >> 3;            // 0..31 (staging row)
    const int sk   = (tid & 7) * 4;       // 0..28 (staging k offset)

    for (int k0 = 0; k0 < K; k0 += KT) {
        __syncthreads();                  // protect prev tile's reads
        // stage X tile (64 rows x KT), optional BN scale/shift folded in
        float4 scv, shv;
        if (scale) {
            scv = *(const float4*)&scale[k0 + sk];
            shv = *(const float4*)&shift[k0 + sk];
        }
#pragma unroll
        for (int h = 0; h < 2; ++h) {
            const int r = srow + h * 32;
            float4 v = *(const float4*)&X[(size_t)(row0 + r) * K + k0 + sk];
            if (scale) {
                v.x = fmaf(v.x, scv.x, shv.x);
                v.y = fmaf(v.y, scv.y, shv.y);
                v.z = fmaf(v.z, scv.z, shv.z);
                v.w = fmaf(v.w, scv.w, shv.w);
            }
            *(float4*)&sx[r * RS + sk] = v;
        }
        // stage W tile (KT x 128) — contiguous 16KB block, flat coalesced copy
        const float* Wt = W + (size_t)k0 * Hh;
#pragma unroll
        for (int h = 0; h < 4; ++h) {
            const int f4 = tid + h * 256;
            *(float4*)&sw[f4 * 4] = *(const float4*)&Wt[f4 * 4];
        }
        __syncthreads();

#pragma unroll
        for (int kk = 0; kk < KT; ++kk) {
            const float4 b0 = *(const float4*)&sw[kk * Hh + 4 * tc];
            const float4 b1 = *(const float4*)&sw[kk * Hh + 64 + 4 * tc];
            float a[4];
#pragma unroll
            for (int i = 0; i < 4; ++i) a[i] = sx[(4 * tr + i) * RS + kk];
#pragma unroll
            for (int i = 0; i < 4; ++i) {
                acc[i][0] = fmaf(a[i], b0.x, acc[i][0]);
                acc[i][1] = fmaf(a[i], b0.y, acc[i][1]);
                acc[i][2] = fmaf(a[i], b0.z, acc[i][2]);
                acc[i][3] = fmaf(a[i], b0.w, acc[i][3]);
                acc[i][4] = fmaf(a[i], b1.x, acc[i][4]);
                acc[i][5] = fmaf(a[i], b1.y, acc[i][5]);
                acc[i][6] = fmaf(a[i], b1.z, acc[i][6]);
                acc[i][7] = fmaf(a[i], b1.w, acc[i][7]);
            }
        }
    }

#pragma unroll
    for (int i = 0; i < 4; ++i) {
        const size_t ro = (size_t)(row0 + 4 * tr + i) * Hh;
        *(float4*)&Y[ro + 4 * tc]      = make_float4(acc[i][0], acc[i][1], acc[i][2], acc[i][3]);
        *(float4*)&Y[ro + 64 + 4 * tc] = make_float4(acc[i][4], acc[i][5], acc[i][6], acc[i][7]);
    }
}

// ---------------------------------------------------------------------------
// K5: aggregation. One wave per node; lane owns channels (2*lane, 2*lane+1);
// all 4 batches per edge. Epilogue: +bias, ReLU, store, BN partial stats.
__global__ __launch_bounds__(256) void k_agg(const float* __restrict__ Hin,
                                             const int* __restrict__ rowptr,
                                             const int* __restrict__ csr_src,
                                             const float* __restrict__ csr_norm,
                                             const float* __restrict__ bias,
                                             float* __restrict__ Hout,
                                             float* __restrict__ gsum,
                                             float* __restrict__ gsq) {
    __shared__ float lsum[Hh], lsq[Hh];
    if (threadIdx.x < Hh) { lsum[threadIdx.x] = 0.f; lsq[threadIdx.x] = 0.f; }
    __syncthreads();

    const int wave = threadIdx.x >> 6;
    const int lane = threadIdx.x & 63;
    const int v = blockIdx.x * 4 + wave;
    const int c0 = lane * 2;

    if (v < Nn) {
        float a0[Bb], a1[Bb];
#pragma unroll
        for (int b = 0; b < Bb; ++b) { a0[b] = 0.f; a1[b] = 0.f; }
        const int beg = rowptr[v], end = rowptr[v + 1];
        for (int e = beg; e < end; ++e) {
            const int s = csr_src[e];
            const float nm = csr_norm[e];
#pragma unroll
            for (int b = 0; b < Bb; ++b) {
                const float2 hv = *(const float2*)(Hin + ((size_t)b * Nn + s) * Hh + c0);
                a0[b] = fmaf(nm, hv.x, a0[b]);
                a1[b] = fmaf(nm, hv.y, a1[b]);
            }
        }
        const float bias0 = bias[c0], bias1 = bias[c0 + 1];
        float t0 = 0.f, t1 = 0.f, q0 = 0.f, q1 = 0.f;
#pragma unroll
        for (int b = 0; b < Bb; ++b) {
            const float y0 = fmaxf(a0[b] + bias0, 0.f);
            const float y1 = fmaxf(a1[b] + bias1, 0.f);
            *(float2*)(Hout + ((size_t)b * Nn + v) * Hh + c0) = make_float2(y0, y1);
            t0 += y0; t1 += y1; q0 += y0 * y0; q1 += y1 * y1;
        }
        atomicAdd(&lsum[c0], t0);     atomicAdd(&lsum[c0 + 1], t1);
        atomicAdd(&lsq[c0],  q0);     atomicAdd(&lsq[c0 + 1],  q1);
    }
    __syncthreads();
    if (threadIdx.x < Hh) {
        atomicAdd(&gsum[threadIdx.x], lsum[threadIdx.x]);
        atomicAdd(&gsq[threadIdx.x],  lsq[threadIdx.x]);
    }
}

// ---------------------------------------------------------------------------
// K6: BN finalize -> per-channel scale/shift
__global__ void k_bnfin(const float* __restrict__ gsum, const float* __restrict__ gsq,
                        const float* __restrict__ gamma, const float* __restrict__ beta,
                        float* __restrict__ scale, float* __restrict__ shift) {
    const int c = threadIdx.x;
    const float inv = 1.0f / (float)(Bb * Nn);
    const float mu  = gsum[c] * inv;
    const float var = gsq[c] * inv - mu * mu;   // biased variance (torch BN fwd)
    const float sc  = gamma[c] * rsqrtf(var + BN_EPS);
    scale[c] = sc;
    shift[c] = beta[c] - mu * sc;
}

// ---------------------------------------------------------------------------
// K7: classifier: out[row] = sum_c (h*scale+shift)[c]*Wc[c] + bc. Wave per row.
__global__ __launch_bounds__(256) void k_cls(const float* __restrict__ Hin,
                                             const float* __restrict__ scale,
                                             const float* __restrict__ shift,
                                             const float* __restrict__ Wc,
                                             const float* __restrict__ bc,
                                             float* __restrict__ out) {
    const int wave = threadIdx.x >> 6;
    const int lane = threadIdx.x & 63;
    const size_t row = (size_t)blockIdx.x * 4 + wave;
    if (row >= (size_t)Bb * Nn) return;
    const int c0 = lane * 2;
    const float2 h = *(const float2*)(Hin + row * Hh + c0);
    float p = (h.x * scale[c0] + shift[c0]) * Wc[c0] +
              (h.y * scale[c0 + 1] + shift[c0 + 1]) * Wc[c0 + 1];
#pragma unroll
    for (int off = 32; off; off >>= 1) p += __shfl_down(p, off);
    if (lane == 0) out[row] = p + bc[0];
}

// ---------------------------------------------------------------------------
extern "C" void kernel_launch(void* const* d_in, const int* in_sizes, int n_in,
                              void* d_out, int out_size, void* d_ws, size_t ws_size,
                              hipStream_t stream) {
    const float* x      = (const float*)d_in[0];
    const int*   ei     = (const int*)d_in[1];
    const float* W1     = (const float*)d_in[2];
    const float* b1     = (const float*)d_in[3];
    const float* W2     = (const float*)d_in[4];
    const float* b2     = (const float*)d_in[5];
    const float* gamma1 = (const float*)d_in[6];
    const float* beta1  = (const float*)d_in[7];
    const float* gamma2 = (const float*)d_in[8];
    const float* beta2  = (const float*)d_in[9];
    const float* Wc     = (const float*)d_in[10];
    const float* bc     = (const float*)d_in[11];
    float* out = (float*)d_out;

    const int E = in_sizes[1] / 2;
    const int* src = ei;
    const int* dst = ei + E;

    char* ws = (char*)d_ws;
    size_t off = 0;
    auto alloc = [&](size_t bytes) -> char* {
        char* p = ws + off;
        off += (bytes + 255) & ~(size_t)255;
        return p;
    };
    int*   deg      = (int*)  alloc((size_t)Nn * 4);
    int*   cursor   = (int*)  alloc((size_t)Nn * 4);
    int*   rowptr   = (int*)  alloc((size_t)(Nn + 1) * 4);
    float* dinv     = (float*)alloc((size_t)Nn * 4);
    int*   csr_src  = (int*)  alloc((size_t)(E + Nn) * 4);
    float* csr_norm = (float*)alloc((size_t)(E + Nn) * 4);
    float* stats    = (float*)alloc((size_t)8 * Hh * 4);
    float* gsum1 = stats,          *gsq1 = stats + Hh;
    float* scale1 = stats + 2*Hh,  *shift1 = stats + 3*Hh;
    float* gsum2 = stats + 4*Hh,   *gsq2 = stats + 5*Hh;
    float* scale2 = stats + 6*Hh,  *shift2 = stats + 7*Hh;
    float* bufA = (float*)alloc((size_t)Bb * Nn * Hh * 4);
    float* bufB = (float*)alloc((size_t)Bb * Nn * Hh * 4);

    (void)hipMemsetAsync(deg, 0, (size_t)Nn * 4, stream);
    (void)hipMemsetAsync(gsum1, 0, (size_t)2 * Hh * 4, stream);
    (void)hipMemsetAsync(gsum2, 0, (size_t)2 * Hh * 4, stream);

    k_deg<<<(E + 255) / 256, 256, 0, stream>>>(dst, E, deg);
    k_scan<<<1, 1024, 0, stream>>>(deg, rowptr, cursor, dinv);
    k_fill<<<(E + Nn + 255) / 256, 256, 0, stream>>>(src, dst, E, dinv, cursor,
                                                     csr_src, csr_norm);

    // Layer 1
    k_gemm<Ff><<<(Bb * Nn) / 64, 256, 0, stream>>>(x, W1, nullptr, nullptr, bufA);
    k_agg<<<(Nn + 3) / 4, 256, 0, stream>>>(bufA, rowptr, csr_src, csr_norm, b1,
                                            bufB, gsum1, gsq1);
    k_bnfin<<<1, Hh, 0, stream>>>(gsum1, gsq1, gamma1, beta1, scale1, shift1);

    // Layer 2 (BN1 applied on GEMM input load)
    k_gemm<Hh><<<(Bb * Nn) / 64, 256, 0, stream>>>(bufB, W2, scale1, shift1, bufA);
    k_agg<<<(Nn + 3) / 4, 256, 0, stream>>>(bufA, rowptr, csr_src, csr_norm, b2,
                                            bufB, gsum2, gsq2);
    k_bnfin<<<1, Hh, 0, stream>>>(gsum2, gsq2, gamma2, beta2, scale2, shift2);

    // Classifier (BN2 applied inline)
    k_cls<<<(Bb * Nn + 3) / 4, 256, 0, stream>>>(bufB, scale2, shift2, Wc, bc, out);
}

// Round 4
// 328.510 us; speedup vs baseline: 2.0462x; 1.5022x over previous
//
#include <hip/hip_runtime.h>

// Problem constants (fixed by setup_inputs)
constexpr int Bb = 4;
constexpr int Nn = 20000;
constexpr int Ff = 64;
constexpr int Hh = 128;
constexpr float BN_EPS = 1e-5f;

// bf16 helpers (RNE pack, cheap unpack)
__device__ inline unsigned f2bf(float f) {
    unsigned u = __float_as_uint(f);
    return (u + 0x7fffu + ((u >> 16) & 1u)) >> 16;
}
__device__ inline unsigned pack2(float lo, float hi) { return f2bf(lo) | (f2bf(hi) << 16); }
__device__ inline float bf_lo(unsigned w) { return __uint_as_float(w << 16); }
__device__ inline float bf_hi(unsigned w) { return __uint_as_float(w & 0xffff0000u); }

// ---------------------------------------------------------------------------
// K1: degree count over dst
__global__ void k_deg(const int* __restrict__ dst, int E, int* __restrict__ deg) {
    int e = blockIdx.x * blockDim.x + threadIdx.x;
    if (e < E) atomicAdd(&deg[dst[e]], 1);
}

// ---------------------------------------------------------------------------
// K2: single-block tiled exclusive scan over (deg[v]+1) -> rowptr, cursor, dinv
__global__ void k_scan(const int* __restrict__ deg, int* __restrict__ rowptr,
                       int* __restrict__ cursor, float* __restrict__ dinv) {
    __shared__ int tile[1024];
    __shared__ int carry_s;
    if (threadIdx.x == 0) carry_s = 0;
    __syncthreads();
    for (int base = 0; base < Nn; base += 1024) {
        const int i = base + (int)threadIdx.x;
        const int cnt = (i < Nn) ? (deg[i] + 1) : 0;  // +1 = self loop
        tile[threadIdx.x] = cnt;
        __syncthreads();
        for (int offd = 1; offd < 1024; offd <<= 1) {
            int t = (threadIdx.x >= (unsigned)offd) ? tile[threadIdx.x - offd] : 0;
            __syncthreads();
            tile[threadIdx.x] += t;
            __syncthreads();
        }
        const int incl = tile[threadIdx.x];
        const int c = carry_s;
        __syncthreads();
        if (threadIdx.x == 1023) carry_s = c + incl;
        if (i < Nn) {
            const int excl = c + incl - cnt;
            rowptr[i] = excl;
            cursor[i] = excl;
            dinv[i]   = rsqrtf((float)cnt);
        }
        __syncthreads();
    }
    if (threadIdx.x == 0) rowptr[Nn] = carry_s;
}

// ---------------------------------------------------------------------------
// K3: fill CSR + per-edge norm + per-node nsum (= sum of norms, for BN-fold)
__global__ void k_fill(const int* __restrict__ src, const int* __restrict__ dst, int E,
                       const float* __restrict__ dinv, int* __restrict__ cursor,
                       int* __restrict__ csr_src, float* __restrict__ csr_norm,
                       float* __restrict__ nsum) {
    int t = blockIdx.x * blockDim.x + threadIdx.x;
    int s, d;
    if (t < E) { s = src[t]; d = dst[t]; }
    else if (t < E + Nn) { s = d = t - E; }
    else return;
    int pos = atomicAdd(&cursor[d], 1);
    const float nm = dinv[s] * dinv[d];
    csr_src[pos]  = s;
    csr_norm[pos] = nm;
    atomicAdd(&nsum[d], nm);
}

// ---------------------------------------------------------------------------
// K4: convert x [B][N][64] fp32 -> xb [N][B][64] bf16 (node-major interleave)
__global__ void k_cvt(const float* __restrict__ x, unsigned* __restrict__ xb) {
    const int t = blockIdx.x * 256 + threadIdx.x;   // enumerates B*N*32 uint outputs
    if (t >= Bb * Nn * 32) return;
    const int c2 = t & 31;
    const int bn = t >> 5;
    const int n  = bn % Nn;
    const int b  = bn / Nn;
    const float2 v = *(const float2*)&x[(size_t)t * 2];
    xb[((size_t)n * Bb + b) * 32 + c2] = pack2(v.x, v.y);
}

// ---------------------------------------------------------------------------
// K5a: aggregate xb (64ch bf16, node-major) -> aggX fp32 [80000][64]
// Wave per node; lane l: batch=l>>4, channels 4*(l&15)..+3. One dwordx2 per
// edge covers all batches+channels (512B contiguous). Edge loop unrolled x4.
__global__ __launch_bounds__(256) void k_agg1(const unsigned* __restrict__ xb,
                                              const int* __restrict__ rowptr,
                                              const int* __restrict__ csr_src,
                                              const float* __restrict__ csr_norm,
                                              float* __restrict__ aggX) {
    const int wave = threadIdx.x >> 6, lane = threadIdx.x & 63;
    const int v = blockIdx.x * 4 + wave;
    if (v >= Nn) return;
    const int beg = rowptr[v], end = rowptr[v + 1];
    float a0 = 0.f, a1 = 0.f, a2 = 0.f, a3 = 0.f;
    int e = beg;
    for (; e + 4 <= end; e += 4) {
        const int s0 = csr_src[e], s1 = csr_src[e + 1], s2 = csr_src[e + 2], s3 = csr_src[e + 3];
        const uint2 w0 = *(const uint2*)(xb + (size_t)s0 * 128 + lane * 2);
        const uint2 w1 = *(const uint2*)(xb + (size_t)s1 * 128 + lane * 2);
        const uint2 w2 = *(const uint2*)(xb + (size_t)s2 * 128 + lane * 2);
        const uint2 w3 = *(const uint2*)(xb + (size_t)s3 * 128 + lane * 2);
        const float n0 = csr_norm[e], n1 = csr_norm[e + 1], n2 = csr_norm[e + 2], n3 = csr_norm[e + 3];
        a0 = fmaf(n0, bf_lo(w0.x), a0); a1 = fmaf(n0, bf_hi(w0.x), a1);
        a2 = fmaf(n0, bf_lo(w0.y), a2); a3 = fmaf(n0, bf_hi(w0.y), a3);
        a0 = fmaf(n1, bf_lo(w1.x), a0); a1 = fmaf(n1, bf_hi(w1.x), a1);
        a2 = fmaf(n1, bf_lo(w1.y), a2); a3 = fmaf(n1, bf_hi(w1.y), a3);
        a0 = fmaf(n2, bf_lo(w2.x), a0); a1 = fmaf(n2, bf_hi(w2.x), a1);
        a2 = fmaf(n2, bf_lo(w2.y), a2); a3 = fmaf(n2, bf_hi(w2.y), a3);
        a0 = fmaf(n3, bf_lo(w3.x), a0); a1 = fmaf(n3, bf_hi(w3.x), a1);
        a2 = fmaf(n3, bf_lo(w3.y), a2); a3 = fmaf(n3, bf_hi(w3.y), a3);
    }
    for (; e < end; ++e) {
        const int s = csr_src[e];
        const float nm = csr_norm[e];
        const uint2 w = *(const uint2*)(xb + (size_t)s * 128 + lane * 2);
        a0 = fmaf(nm, bf_lo(w.x), a0); a1 = fmaf(nm, bf_hi(w.x), a1);
        a2 = fmaf(nm, bf_lo(w.y), a2); a3 = fmaf(nm, bf_hi(w.y), a3);
    }
    *(float4*)&aggX[((size_t)v * 4 + (lane >> 4)) * 64 + (lane & 15) * 4] =
        make_float4(a0, a1, a2, a3);
}

// ---------------------------------------------------------------------------
// K5b: aggregate hb (128ch bf16, node-major) -> aggH fp32 [80000][128]
// lane l: batch=l>>4, channels 8*(l&15)..+7. One dwordx4 per edge (1KB).
__global__ __launch_bounds__(256) void k_agg2(const unsigned* __restrict__ hb,
                                              const int* __restrict__ rowptr,
                                              const int* __restrict__ csr_src,
                                              const float* __restrict__ csr_norm,
                                              float* __restrict__ aggH) {
    const int wave = threadIdx.x >> 6, lane = threadIdx.x & 63;
    const int v = blockIdx.x * 4 + wave;
    if (v >= Nn) return;
    const int beg = rowptr[v], end = rowptr[v + 1];
    float a[8];
#pragma unroll
    for (int j = 0; j < 8; ++j) a[j] = 0.f;
    int e = beg;
    for (; e + 4 <= end; e += 4) {
        const int s0 = csr_src[e], s1 = csr_src[e + 1], s2 = csr_src[e + 2], s3 = csr_src[e + 3];
        const uint4 w0 = *(const uint4*)(hb + (size_t)s0 * 256 + lane * 4);
        const uint4 w1 = *(const uint4*)(hb + (size_t)s1 * 256 + lane * 4);
        const uint4 w2 = *(const uint4*)(hb + (size_t)s2 * 256 + lane * 4);
        const uint4 w3 = *(const uint4*)(hb + (size_t)s3 * 256 + lane * 4);
        const float n0 = csr_norm[e], n1 = csr_norm[e + 1], n2 = csr_norm[e + 2], n3 = csr_norm[e + 3];
        a[0] = fmaf(n0, bf_lo(w0.x), a[0]); a[1] = fmaf(n0, bf_hi(w0.x), a[1]);
        a[2] = fmaf(n0, bf_lo(w0.y), a[2]); a[3] = fmaf(n0, bf_hi(w0.y), a[3]);
        a[4] = fmaf(n0, bf_lo(w0.z), a[4]); a[5] = fmaf(n0, bf_hi(w0.z), a[5]);
        a[6] = fmaf(n0, bf_lo(w0.w), a[6]); a[7] = fmaf(n0, bf_hi(w0.w), a[7]);
        a[0] = fmaf(n1, bf_lo(w1.x), a[0]); a[1] = fmaf(n1, bf_hi(w1.x), a[1]);
        a[2] = fmaf(n1, bf_lo(w1.y), a[2]); a[3] = fmaf(n1, bf_hi(w1.y), a[3]);
        a[4] = fmaf(n1, bf_lo(w1.z), a[4]); a[5] = fmaf(n1, bf_hi(w1.z), a[5]);
        a[6] = fmaf(n1, bf_lo(w1.w), a[6]); a[7] = fmaf(n1, bf_hi(w1.w), a[7]);
        a[0] = fmaf(n2, bf_lo(w2.x), a[0]); a[1] = fmaf(n2, bf_hi(w2.x), a[1]);
        a[2] = fmaf(n2, bf_lo(w2.y), a[2]); a[3] = fmaf(n2, bf_hi(w2.y), a[3]);
        a[4] = fmaf(n2, bf_lo(w2.z), a[4]); a[5] = fmaf(n2, bf_hi(w2.z), a[5]);
        a[6] = fmaf(n2, bf_lo(w2.w), a[6]); a[7] = fmaf(n2, bf_hi(w2.w), a[7]);
        a[0] = fmaf(n3, bf_lo(w3.x), a[0]); a[1] = fmaf(n3, bf_hi(w3.x), a[1]);
        a[2] = fmaf(n3, bf_lo(w3.y), a[2]); a[3] = fmaf(n3, bf_hi(w3.y), a[3]);
        a[4] = fmaf(n3, bf_lo(w3.z), a[4]); a[5] = fmaf(n3, bf_hi(w3.z), a[5]);
        a[6] = fmaf(n3, bf_lo(w3.w), a[6]); a[7] = fmaf(n3, bf_hi(w3.w), a[7]);
    }
    for (; e < end; ++e) {
        const int s = csr_src[e];
        const float nm = csr_norm[e];
        const uint4 w = *(const uint4*)(hb + (size_t)s * 256 + lane * 4);
        a[0] = fmaf(nm, bf_lo(w.x), a[0]); a[1] = fmaf(nm, bf_hi(w.x), a[1]);
        a[2] = fmaf(nm, bf_lo(w.y), a[2]); a[3] = fmaf(nm, bf_hi(w.y), a[3]);
        a[4] = fmaf(nm, bf_lo(w.z), a[4]); a[5] = fmaf(nm, bf_hi(w.z), a[5]);
        a[6] = fmaf(nm, bf_lo(w.w), a[6]); a[7] = fmaf(nm, bf_hi(w.w), a[7]);
    }
    const size_t ro = ((size_t)v * 4 + (lane >> 4)) * 128 + (lane & 15) * 8;
    *(float4*)&aggH[ro]     = make_float4(a[0], a[1], a[2], a[3]);
    *(float4*)&aggH[ro + 4] = make_float4(a[4], a[5], a[6], a[7]);
}

// ---------------------------------------------------------------------------
// K6: GEMM  Y[rows,128] = A[rows,K] @ W[K,128], register-tiled 64x128 tile.
// AFFINE: A' = A*sc[k] + nsum[node]*sh[k]; rows are node-major so node = row>>2.
// Epilogue: +bias, ReLU, BN stats (gsum/gsq atomics); OUT_BF16 -> packed bf16.
template <int K, bool AFFINE, bool OUT_BF16>
__global__ __launch_bounds__(256) void k_gemm(const float* __restrict__ A,
                                              const float* __restrict__ W,
                                              const float* __restrict__ sc,
                                              const float* __restrict__ sh,
                                              const float* __restrict__ nsum,
                                              const float* __restrict__ bias,
                                              void* __restrict__ Yout,
                                              float* __restrict__ gsum,
                                              float* __restrict__ gsq) {
    constexpr int KT = 32;
    constexpr int RS = KT + 4;
    __shared__ float sx[64 * RS];
    __shared__ float sw[KT * Hh];
    __shared__ float lsum[Hh], lsq[Hh];

    const int tid = threadIdx.x;
    if (tid < Hh) { lsum[tid] = 0.f; lsq[tid] = 0.f; }
    const int tr = tid >> 4;
    const int tc = tid & 15;
    const int row0 = blockIdx.x * 64;

    float acc[4][8];
#pragma unroll
    for (int i = 0; i < 4; ++i)
#pragma unroll
        for (int j = 0; j < 8; ++j) acc[i][j] = 0.f;

    const int srow = tid >> 3;
    const int sk   = (tid & 7) * 4;

    for (int k0 = 0; k0 < K; k0 += KT) {
        __syncthreads();
        float4 scv, shv;
        if (AFFINE) {
            scv = *(const float4*)&sc[k0 + sk];
            shv = *(const float4*)&sh[k0 + sk];
        }
#pragma unroll
        for (int h = 0; h < 2; ++h) {
            const int r = srow + h * 32;
            float4 v = *(const float4*)&A[(size_t)(row0 + r) * K + k0 + sk];
            if (AFFINE) {
                // rows are node-major (r = n*4 + b) -> node index is row>>2
                const float ns = nsum[(row0 + r) >> 2];
                v.x = fmaf(v.x, scv.x, ns * shv.x);
                v.y = fmaf(v.y, scv.y, ns * shv.y);
                v.z = fmaf(v.z, scv.z, ns * shv.z);
                v.w = fmaf(v.w, scv.w, ns * shv.w);
            }
            *(float4*)&sx[r * RS + sk] = v;
        }
        const float* Wt = W + (size_t)k0 * Hh;
#pragma unroll
        for (int h = 0; h < 4; ++h) {
            const int f4 = tid + h * 256;
            *(float4*)&sw[f4 * 4] = *(const float4*)&Wt[f4 * 4];
        }
        __syncthreads();

#pragma unroll
        for (int kk = 0; kk < KT; ++kk) {
            const float4 b0 = *(const float4*)&sw[kk * Hh + 4 * tc];
            const float4 b1 = *(const float4*)&sw[kk * Hh + 64 + 4 * tc];
            float av[4];
#pragma unroll
            for (int i = 0; i < 4; ++i) av[i] = sx[(4 * tr + i) * RS + kk];
#pragma unroll
            for (int i = 0; i < 4; ++i) {
                acc[i][0] = fmaf(av[i], b0.x, acc[i][0]);
                acc[i][1] = fmaf(av[i], b0.y, acc[i][1]);
                acc[i][2] = fmaf(av[i], b0.z, acc[i][2]);
                acc[i][3] = fmaf(av[i], b0.w, acc[i][3]);
                acc[i][4] = fmaf(av[i], b1.x, acc[i][4]);
                acc[i][5] = fmaf(av[i], b1.y, acc[i][5]);
                acc[i][6] = fmaf(av[i], b1.z, acc[i][6]);
                acc[i][7] = fmaf(av[i], b1.w, acc[i][7]);
            }
        }
    }

    const float4 bA = *(const float4*)&bias[4 * tc];
    const float4 bB = *(const float4*)&bias[64 + 4 * tc];
    float s0 = 0.f, s1 = 0.f, s2 = 0.f, s3 = 0.f, s4 = 0.f, s5 = 0.f, s6 = 0.f, s7 = 0.f;
    float q0 = 0.f, q1 = 0.f, q2 = 0.f, q3 = 0.f, q4 = 0.f, q5 = 0.f, q6 = 0.f, q7 = 0.f;
#pragma unroll
    for (int i = 0; i < 4; ++i) {
        const size_t r = (size_t)(row0 + 4 * tr + i);
        const float y0 = fmaxf(acc[i][0] + bA.x, 0.f);
        const float y1 = fmaxf(acc[i][1] + bA.y, 0.f);
        const float y2 = fmaxf(acc[i][2] + bA.z, 0.f);
        const float y3 = fmaxf(acc[i][3] + bA.w, 0.f);
        const float z0 = fmaxf(acc[i][4] + bB.x, 0.f);
        const float z1 = fmaxf(acc[i][5] + bB.y, 0.f);
        const float z2 = fmaxf(acc[i][6] + bB.z, 0.f);
        const float z3 = fmaxf(acc[i][7] + bB.w, 0.f);
        s0 += y0; s1 += y1; s2 += y2; s3 += y3; s4 += z0; s5 += z1; s6 += z2; s7 += z3;
        q0 += y0 * y0; q1 += y1 * y1; q2 += y2 * y2; q3 += y3 * y3;
        q4 += z0 * z0; q5 += z1 * z1; q6 += z2 * z2; q7 += z3 * z3;
        if (OUT_BF16) {
            unsigned* Yb = (unsigned*)Yout;
            *(uint2*)&Yb[r * 64 + 2 * tc]      = make_uint2(pack2(y0, y1), pack2(y2, y3));
            *(uint2*)&Yb[r * 64 + 32 + 2 * tc] = make_uint2(pack2(z0, z1), pack2(z2, z3));
        } else {
            float* Yf = (float*)Yout;
            *(float4*)&Yf[r * Hh + 4 * tc]      = make_float4(y0, y1, y2, y3);
            *(float4*)&Yf[r * Hh + 64 + 4 * tc] = make_float4(z0, z1, z2, z3);
        }
    }
    atomicAdd(&lsum[4 * tc],     s0); atomicAdd(&lsum[4 * tc + 1], s1);
    atomicAdd(&lsum[4 * tc + 2], s2); atomicAdd(&lsum[4 * tc + 3], s3);
    atomicAdd(&lsum[64 + 4 * tc],     s4); atomicAdd(&lsum[64 + 4 * tc + 1], s5);
    atomicAdd(&lsum[64 + 4 * tc + 2], s6); atomicAdd(&lsum[64 + 4 * tc + 3], s7);
    atomicAdd(&lsq[4 * tc],     q0); atomicAdd(&lsq[4 * tc + 1], q1);
    atomicAdd(&lsq[4 * tc + 2], q2); atomicAdd(&lsq[4 * tc + 3], q3);
    atomicAdd(&lsq[64 + 4 * tc],     q4); atomicAdd(&lsq[64 + 4 * tc + 1], q5);
    atomicAdd(&lsq[64 + 4 * tc + 2], q6); atomicAdd(&lsq[64 + 4 * tc + 3], q7);
    __syncthreads();
    if (tid < Hh) atomicAdd(&gsum[tid], lsum[tid]);
    else if (tid < 2 * Hh) atomicAdd(&gsq[tid - Hh], lsq[tid - Hh]);
}

// ---------------------------------------------------------------------------
// K7: BN finalize -> per-channel scale/shift
__global__ void k_bnfin(const float* __restrict__ gsum, const float* __restrict__ gsq,
                        const float* __restrict__ gamma, const float* __restrict__ beta,
                        float* __restrict__ scale, float* __restrict__ shift) {
    const int c = threadIdx.x;
    const float inv = 1.0f / (float)(Bb * Nn);
    const float mu  = gsum[c] * inv;
    const float var = gsq[c] * inv - mu * mu;
    const float s   = gamma[c] * rsqrtf(var + BN_EPS);
    scale[c] = s;
    shift[c] = beta[c] - mu * s;
}

// ---------------------------------------------------------------------------
// K8: classifier. Rows node-major (r = n*4+b); out[b*Nn+n].
__global__ __launch_bounds__(256) void k_cls(const float* __restrict__ Hin,
                                             const float* __restrict__ scale,
                                             const float* __restrict__ shift,
                                             const float* __restrict__ Wc,
                                             const float* __restrict__ bc,
                                             float* __restrict__ out) {
    const int wave = threadIdx.x >> 6;
    const int lane = threadIdx.x & 63;
    const size_t row = (size_t)blockIdx.x * 4 + wave;
    if (row >= (size_t)Bb * Nn) return;
    const int c0 = lane * 2;
    const float2 h = *(const float2*)(Hin + row * Hh + c0);
    float p = (h.x * scale[c0] + shift[c0]) * Wc[c0] +
              (h.y * scale[c0 + 1] + shift[c0 + 1]) * Wc[c0 + 1];
#pragma unroll
    for (int off = 32; off; off >>= 1) p += __shfl_down(p, off);
    if (lane == 0) {
        const int n = (int)(row >> 2), b = (int)(row & 3);
        out[(size_t)b * Nn + n] = p + bc[0];
    }
}

// ---------------------------------------------------------------------------
extern "C" void kernel_launch(void* const* d_in, const int* in_sizes, int n_in,
                              void* d_out, int out_size, void* d_ws, size_t ws_size,
                              hipStream_t stream) {
    const float* x      = (const float*)d_in[0];
    const int*   ei     = (const int*)d_in[1];
    const float* W1     = (const float*)d_in[2];
    const float* b1     = (const float*)d_in[3];
    const float* W2     = (const float*)d_in[4];
    const float* b2     = (const float*)d_in[5];
    const float* gamma1 = (const float*)d_in[6];
    const float* beta1  = (const float*)d_in[7];
    const float* gamma2 = (const float*)d_in[8];
    const float* beta2  = (const float*)d_in[9];
    const float* Wc     = (const float*)d_in[10];
    const float* bc     = (const float*)d_in[11];
    float* out = (float*)d_out;

    const int E = in_sizes[1] / 2;
    const int* src = ei;
    const int* dst = ei + E;

    char* ws = (char*)d_ws;
    size_t off = 0;
    auto alloc = [&](size_t bytes) -> char* {
        char* p = ws + off;
        off += (bytes + 255) & ~(size_t)255;
        return p;
    };
    int*      deg      = (int*)     alloc((size_t)Nn * 4);
    int*      cursor   = (int*)     alloc((size_t)Nn * 4);
    int*      rowptr   = (int*)     alloc((size_t)(Nn + 1) * 4);
    float*    dinv     = (float*)   alloc((size_t)Nn * 4);
    float*    nsum     = (float*)   alloc((size_t)Nn * 4);
    int*      csr_src  = (int*)     alloc((size_t)(E + Nn) * 4);
    float*    csr_norm = (float*)   alloc((size_t)(E + Nn) * 4);
    float*    stats    = (float*)   alloc((size_t)8 * Hh * 4);
    float* gsum1 = stats,           *gsq1 = stats + Hh;
    float* scale1 = stats + 2 * Hh, *shift1 = stats + 3 * Hh;
    float* gsum2 = stats + 4 * Hh,  *gsq2 = stats + 5 * Hh;
    float* scale2 = stats + 6 * Hh, *shift2 = stats + 7 * Hh;
    unsigned* xb   = (unsigned*)alloc((size_t)Nn * Bb * 32 * 4);   // bf16 x, node-major
    float*    aggX = (float*)   alloc((size_t)Bb * Nn * Ff * 4);   // fp32 [80000][64]
    unsigned* h1b  = (unsigned*)alloc((size_t)Nn * Bb * 64 * 4);   // bf16 h1, node-major
    float*    aggH = (float*)   alloc((size_t)Bb * Nn * Hh * 4);   // fp32 [80000][128]
    float*    bufB = (float*)   alloc((size_t)Bb * Nn * Hh * 4);   // fp32 conv2-out

    (void)hipMemsetAsync(deg, 0, (size_t)Nn * 4, stream);
    (void)hipMemsetAsync(nsum, 0, (size_t)Nn * 4, stream);
    (void)hipMemsetAsync(gsum1, 0, (size_t)2 * Hh * 4, stream);
    (void)hipMemsetAsync(gsum2, 0, (size_t)2 * Hh * 4, stream);

    k_deg<<<(E + 255) / 256, 256, 0, stream>>>(dst, E, deg);
    k_scan<<<1, 1024, 0, stream>>>(deg, rowptr, cursor, dinv);
    k_fill<<<(E + Nn + 255) / 256, 256, 0, stream>>>(src, dst, E, dinv, cursor,
                                                     csr_src, csr_norm, nsum);
    k_cvt<<<(Bb * Nn * 32 + 255) / 256, 256, 0, stream>>>(x, xb);

    // Layer 1: agg(x) @ W1  (+b1, ReLU, BN1 stats, bf16 out)
    k_agg1<<<(Nn + 3) / 4, 256, 0, stream>>>(xb, rowptr, csr_src, csr_norm, aggX);
    k_gemm<Ff, false, true><<<(Bb * Nn) / 64, 256, 0, stream>>>(
        aggX, W1, nullptr, nullptr, nullptr, b1, h1b, gsum1, gsq1);
    k_bnfin<<<1, Hh, 0, stream>>>(gsum1, gsq1, gamma1, beta1, scale1, shift1);

    // Layer 2: (sc1*agg(h1) + nsum*sh1) @ W2  (+b2, ReLU, BN2 stats, fp32 out)
    k_agg2<<<(Nn + 3) / 4, 256, 0, stream>>>(h1b, rowptr, csr_src, csr_norm, aggH);
    k_gemm<Hh, true, false><<<(Bb * Nn) / 64, 256, 0, stream>>>(
        aggH, W2, scale1, shift1, nsum, b2, bufB, gsum2, gsq2);
    k_bnfin<<<1, Hh, 0, stream>>>(gsum2, gsq2, gamma2, beta2, scale2, shift2);

    // Classifier (BN2 inline)
    k_cls<<<(Bb * Nn + 3) / 4, 256, 0, stream>>>(bufB, scale2, shift2, Wc, bc, out);
}

// Round 5
// 298.674 us; speedup vs baseline: 2.2506x; 1.0999x over previous
//
#include <hip/hip_runtime.h>

// Problem constants (fixed by setup_inputs)
constexpr int Bb = 4;
constexpr int Nn = 20000;
constexpr int Ff = 64;
constexpr int Hh = 128;
constexpr float BN_EPS = 1e-5f;

typedef __attribute__((ext_vector_type(8))) short bf16x8;
typedef __attribute__((ext_vector_type(4))) float f32x4;

// bf16 helpers (RNE pack, cheap unpack)
__device__ inline unsigned f2bf(float f) {
    unsigned u = __float_as_uint(f);
    return (u + 0x7fffu + ((u >> 16) & 1u)) >> 16;
}
__device__ inline unsigned pack2(float lo, float hi) { return f2bf(lo) | (f2bf(hi) << 16); }
__device__ inline float bf_lo(unsigned w) { return __uint_as_float(w << 16); }
__device__ inline float bf_hi(unsigned w) { return __uint_as_float(w & 0xffff0000u); }

// ---------------------------------------------------------------------------
// K1: degree count over dst
__global__ void k_deg(const int* __restrict__ dst, int E, int* __restrict__ deg) {
    int e = blockIdx.x * blockDim.x + threadIdx.x;
    if (e < E) atomicAdd(&deg[dst[e]], 1);
}

// ---------------------------------------------------------------------------
// K2: single-block tiled exclusive scan over (deg[v]+1) -> rowptr, cursor, dinv
__global__ void k_scan(const int* __restrict__ deg, int* __restrict__ rowptr,
                       int* __restrict__ cursor, float* __restrict__ dinv) {
    __shared__ int tile[1024];
    __shared__ int carry_s;
    if (threadIdx.x == 0) carry_s = 0;
    __syncthreads();
    for (int base = 0; base < Nn; base += 1024) {
        const int i = base + (int)threadIdx.x;
        const int cnt = (i < Nn) ? (deg[i] + 1) : 0;  // +1 = self loop
        tile[threadIdx.x] = cnt;
        __syncthreads();
        for (int offd = 1; offd < 1024; offd <<= 1) {
            int t = (threadIdx.x >= (unsigned)offd) ? tile[threadIdx.x - offd] : 0;
            __syncthreads();
            tile[threadIdx.x] += t;
            __syncthreads();
        }
        const int incl = tile[threadIdx.x];
        const int c = carry_s;
        __syncthreads();
        if (threadIdx.x == 1023) carry_s = c + incl;
        if (i < Nn) {
            const int excl = c + incl - cnt;
            rowptr[i] = excl;
            cursor[i] = excl;
            dinv[i]   = rsqrtf((float)cnt);
        }
        __syncthreads();
    }
    if (threadIdx.x == 0) rowptr[Nn] = carry_s;
}

// ---------------------------------------------------------------------------
// K3: fill CSR + per-edge norm + per-node nsum (= sum of norms, for BN-fold)
__global__ void k_fill(const int* __restrict__ src, const int* __restrict__ dst, int E,
                       const float* __restrict__ dinv, int* __restrict__ cursor,
                       int* __restrict__ csr_src, float* __restrict__ csr_norm,
                       float* __restrict__ nsum) {
    int t = blockIdx.x * blockDim.x + threadIdx.x;
    int s, d;
    if (t < E) { s = src[t]; d = dst[t]; }
    else if (t < E + Nn) { s = d = t - E; }
    else return;
    int pos = atomicAdd(&cursor[d], 1);
    const float nm = dinv[s] * dinv[d];
    csr_src[pos]  = s;
    csr_norm[pos] = nm;
    atomicAdd(&nsum[d], nm);
}

// ---------------------------------------------------------------------------
// K4: convert x [B][N][64] fp32 -> xb [N][B][64] bf16 (node-major interleave)
__global__ void k_cvt(const float* __restrict__ x, unsigned* __restrict__ xb) {
    const int t = blockIdx.x * 256 + threadIdx.x;   // enumerates B*N*32 uint outputs
    if (t >= Bb * Nn * 32) return;
    const int c2 = t & 31;
    const int bn = t >> 5;
    const int n  = bn % Nn;
    const int b  = bn / Nn;
    const float2 v = *(const float2*)&x[(size_t)t * 2];
    xb[((size_t)n * Bb + b) * 32 + c2] = pack2(v.x, v.y);
}

// ---------------------------------------------------------------------------
// K5: weight prep: WT[c][k] = bf16( (FOLD ? sc[k] : 1) * W[k][c] )  (transpose)
template <int K, bool FOLD>
__global__ void k_wt(const float* __restrict__ W, const float* __restrict__ sc,
                     unsigned short* __restrict__ WT) {
    const int t = blockIdx.x * 256 + threadIdx.x;
    if (t >= 128 * K) return;
    const int c = t / K, k = t % K;
    float v = W[(size_t)k * 128 + c];
    if (FOLD) v *= sc[k];
    WT[(size_t)c * K + k] = (unsigned short)f2bf(v);
}

// K5b: shW2[c] = sum_k sh[k] * W2[k][c]   (one block, 128 threads)
__global__ void k_shw(const float* __restrict__ sh, const float* __restrict__ W2,
                      float* __restrict__ shW2) {
    const int c = threadIdx.x;
    float s = 0.f;
    for (int k = 0; k < Hh; ++k) s = fmaf(sh[k], W2[(size_t)k * 128 + c], s);
    shW2[c] = s;
}

// ---------------------------------------------------------------------------
// K6a: aggregate xb (64ch bf16, node-major) -> aggXb bf16 [80000][64]
__global__ __launch_bounds__(256) void k_agg1(const unsigned* __restrict__ xb,
                                              const int* __restrict__ rowptr,
                                              const int* __restrict__ csr_src,
                                              const float* __restrict__ csr_norm,
                                              unsigned short* __restrict__ aggXb) {
    const int wave = threadIdx.x >> 6, lane = threadIdx.x & 63;
    const int v = blockIdx.x * 4 + wave;
    if (v >= Nn) return;
    const int beg = rowptr[v], end = rowptr[v + 1];
    float a0 = 0.f, a1 = 0.f, a2 = 0.f, a3 = 0.f;
    int e = beg;
    for (; e + 4 <= end; e += 4) {
        const int s0 = csr_src[e], s1 = csr_src[e + 1], s2 = csr_src[e + 2], s3 = csr_src[e + 3];
        const uint2 w0 = *(const uint2*)(xb + (size_t)s0 * 128 + lane * 2);
        const uint2 w1 = *(const uint2*)(xb + (size_t)s1 * 128 + lane * 2);
        const uint2 w2 = *(const uint2*)(xb + (size_t)s2 * 128 + lane * 2);
        const uint2 w3 = *(const uint2*)(xb + (size_t)s3 * 128 + lane * 2);
        const float n0 = csr_norm[e], n1 = csr_norm[e + 1], n2 = csr_norm[e + 2], n3 = csr_norm[e + 3];
        a0 = fmaf(n0, bf_lo(w0.x), a0); a1 = fmaf(n0, bf_hi(w0.x), a1);
        a2 = fmaf(n0, bf_lo(w0.y), a2); a3 = fmaf(n0, bf_hi(w0.y), a3);
        a0 = fmaf(n1, bf_lo(w1.x), a0); a1 = fmaf(n1, bf_hi(w1.x), a1);
        a2 = fmaf(n1, bf_lo(w1.y), a2); a3 = fmaf(n1, bf_hi(w1.y), a3);
        a0 = fmaf(n2, bf_lo(w2.x), a0); a1 = fmaf(n2, bf_hi(w2.x), a1);
        a2 = fmaf(n2, bf_lo(w2.y), a2); a3 = fmaf(n2, bf_hi(w2.y), a3);
        a0 = fmaf(n3, bf_lo(w3.x), a0); a1 = fmaf(n3, bf_hi(w3.x), a1);
        a2 = fmaf(n3, bf_lo(w3.y), a2); a3 = fmaf(n3, bf_hi(w3.y), a3);
    }
    for (; e < end; ++e) {
        const int s = csr_src[e];
        const float nm = csr_norm[e];
        const uint2 w = *(const uint2*)(xb + (size_t)s * 128 + lane * 2);
        a0 = fmaf(nm, bf_lo(w.x), a0); a1 = fmaf(nm, bf_hi(w.x), a1);
        a2 = fmaf(nm, bf_lo(w.y), a2); a3 = fmaf(nm, bf_hi(w.y), a3);
    }
    unsigned short* o = aggXb + ((size_t)v * 4 + (lane >> 4)) * 64 + (lane & 15) * 4;
    *(uint2*)o = make_uint2(pack2(a0, a1), pack2(a2, a3));
}

// ---------------------------------------------------------------------------
// K6b: aggregate hb (128ch bf16, node-major) -> aggHb bf16 [80000][128]
__global__ __launch_bounds__(256) void k_agg2(const unsigned* __restrict__ hb,
                                              const int* __restrict__ rowptr,
                                              const int* __restrict__ csr_src,
                                              const float* __restrict__ csr_norm,
                                              unsigned short* __restrict__ aggHb) {
    const int wave = threadIdx.x >> 6, lane = threadIdx.x & 63;
    const int v = blockIdx.x * 4 + wave;
    if (v >= Nn) return;
    const int beg = rowptr[v], end = rowptr[v + 1];
    float a[8];
#pragma unroll
    for (int j = 0; j < 8; ++j) a[j] = 0.f;
    int e = beg;
    for (; e + 4 <= end; e += 4) {
        const int s0 = csr_src[e], s1 = csr_src[e + 1], s2 = csr_src[e + 2], s3 = csr_src[e + 3];
        const uint4 w0 = *(const uint4*)(hb + (size_t)s0 * 256 + lane * 4);
        const uint4 w1 = *(const uint4*)(hb + (size_t)s1 * 256 + lane * 4);
        const uint4 w2 = *(const uint4*)(hb + (size_t)s2 * 256 + lane * 4);
        const uint4 w3 = *(const uint4*)(hb + (size_t)s3 * 256 + lane * 4);
        const float n0 = csr_norm[e], n1 = csr_norm[e + 1], n2 = csr_norm[e + 2], n3 = csr_norm[e + 3];
        a[0] = fmaf(n0, bf_lo(w0.x), a[0]); a[1] = fmaf(n0, bf_hi(w0.x), a[1]);
        a[2] = fmaf(n0, bf_lo(w0.y), a[2]); a[3] = fmaf(n0, bf_hi(w0.y), a[3]);
        a[4] = fmaf(n0, bf_lo(w0.z), a[4]); a[5] = fmaf(n0, bf_hi(w0.z), a[5]);
        a[6] = fmaf(n0, bf_lo(w0.w), a[6]); a[7] = fmaf(n0, bf_hi(w0.w), a[7]);
        a[0] = fmaf(n1, bf_lo(w1.x), a[0]); a[1] = fmaf(n1, bf_hi(w1.x), a[1]);
        a[2] = fmaf(n1, bf_lo(w1.y), a[2]); a[3] = fmaf(n1, bf_hi(w1.y), a[3]);
        a[4] = fmaf(n1, bf_lo(w1.z), a[4]); a[5] = fmaf(n1, bf_hi(w1.z), a[5]);
        a[6] = fmaf(n1, bf_lo(w1.w), a[6]); a[7] = fmaf(n1, bf_hi(w1.w), a[7]);
        a[0] = fmaf(n2, bf_lo(w2.x), a[0]); a[1] = fmaf(n2, bf_hi(w2.x), a[1]);
        a[2] = fmaf(n2, bf_lo(w2.y), a[2]); a[3] = fmaf(n2, bf_hi(w2.y), a[3]);
        a[4] = fmaf(n2, bf_lo(w2.z), a[4]); a[5] = fmaf(n2, bf_hi(w2.z), a[5]);
        a[6] = fmaf(n2, bf_lo(w2.w), a[6]); a[7] = fmaf(n2, bf_hi(w2.w), a[7]);
        a[0] = fmaf(n3, bf_lo(w3.x), a[0]); a[1] = fmaf(n3, bf_hi(w3.x), a[1]);
        a[2] = fmaf(n3, bf_lo(w3.y), a[2]); a[3] = fmaf(n3, bf_hi(w3.y), a[3]);
        a[4] = fmaf(n3, bf_lo(w3.z), a[4]); a[5] = fmaf(n3, bf_hi(w3.z), a[5]);
        a[6] = fmaf(n3, bf_lo(w3.w), a[6]); a[7] = fmaf(n3, bf_hi(w3.w), a[7]);
    }
    for (; e < end; ++e) {
        const int s = csr_src[e];
        const float nm = csr_norm[e];
        const uint4 w = *(const uint4*)(hb + (size_t)s * 256 + lane * 4);
        a[0] = fmaf(nm, bf_lo(w.x), a[0]); a[1] = fmaf(nm, bf_hi(w.x), a[1]);
        a[2] = fmaf(nm, bf_lo(w.y), a[2]); a[3] = fmaf(nm, bf_hi(w.y), a[3]);
        a[4] = fmaf(nm, bf_lo(w.z), a[4]); a[5] = fmaf(nm, bf_hi(w.z), a[5]);
        a[6] = fmaf(nm, bf_lo(w.w), a[6]); a[7] = fmaf(nm, bf_hi(w.w), a[7]);
    }
    unsigned short* o = aggHb + ((size_t)v * 4 + (lane >> 4)) * 128 + (lane & 15) * 8;
    *(uint4*)o = make_uint4(pack2(a[0], a[1]), pack2(a[2], a[3]),
                            pack2(a[4], a[5]), pack2(a[6], a[7]));
}

// ---------------------------------------------------------------------------
// K7: MFMA GEMM. C[64rows x 128] = A[64 x K]_bf16 @ WT^T (WT is [128][K] bf16).
// 4 waves; wave w owns rows w*16..+15. mfma_f32_16x16x32_bf16:
//   A frag: row=lane&15, k=(lane>>4)*8+j ; B frag: col=lane&15, same k
//   C/D:    col=lane&15, row=(lane>>4)*4+reg   [guide §3, m89/m91]
// WT staged frag-linear (64 lanes x 16B contiguous per (tile,kstep) -> conflict-
// free); A staged row-major stride K+8 (2-way, free). One barrier total.
// Epilogue: +bias (+ns*shW2 for L2E), ReLU, BN stats; out bf16 (L1) / fp32 (L2).
template <int K, bool L2E>
__global__ __launch_bounds__(256) void k_mm(const unsigned short* __restrict__ A,
                                            const unsigned short* __restrict__ WT,
                                            const float* __restrict__ bias,
                                            const float* __restrict__ nsum,
                                            const float* __restrict__ shW2,
                                            void* __restrict__ Yout,
                                            float* __restrict__ gsum,
                                            float* __restrict__ gsq) {
    constexpr int NKS = K / 32;
    constexpr int AST = K + 8;
    constexpr int NSLOT = 8 * NKS * 64;
    __shared__ alignas(16) unsigned short sB[NSLOT * 8];
    __shared__ alignas(16) unsigned short sA[64 * AST];
    __shared__ float lsum[128], lsq[128];

    const int tid = threadIdx.x;
    const int row0 = blockIdx.x * 64;
    if (tid < 128) { lsum[tid] = 0.f; lsq[tid] = 0.f; }

#pragma unroll
    for (int i = 0; i < NSLOT / 256; ++i) {
        const int s = tid + i * 256;
        const int l = s & 63;
        const int ks = (s >> 6) % NKS;
        const int ct = (s >> 6) / NKS;
        const int col = ct * 16 + (l & 15);
        const int k = ks * 32 + ((l >> 4) << 3);
        *(uint4*)&sB[s * 8] = *(const uint4*)&WT[(size_t)col * K + k];
    }
#pragma unroll
    for (int i = 0; i < (64 * K / 8) / 256; ++i) {
        const int c = tid + i * 256;
        const int row = c / (K / 8);
        const int k8 = c % (K / 8);
        *(uint4*)&sA[row * AST + k8 * 8] = *(const uint4*)&A[(size_t)(row0 + row) * K + k8 * 8];
    }
    __syncthreads();

    const int w = tid >> 6, lane = tid & 63;
    const int rowL = w * 16 + (lane & 15);
    const int kg = lane >> 4;

    f32x4 acc[8];
#pragma unroll
    for (int t = 0; t < 8; ++t) acc[t] = (f32x4){0.f, 0.f, 0.f, 0.f};

#pragma unroll
    for (int ks = 0; ks < NKS; ++ks) {
        const bf16x8 a = *(const bf16x8*)&sA[rowL * AST + ks * 32 + kg * 8];
#pragma unroll
        for (int t = 0; t < 8; ++t) {
            const bf16x8 b = *(const bf16x8*)&sB[((t * NKS + ks) * 64 + lane) * 8];
            acc[t] = __builtin_amdgcn_mfma_f32_16x16x32_bf16(a, b, acc[t], 0, 0, 0);
        }
    }

    // epilogue
    const int colb = lane & 15;
    const int rbase = w * 16 + kg * 4;        // 4 regs = 4 batches of ONE node
    float ns = 0.f;
    if (L2E) ns = nsum[(row0 + rbase) >> 2];
#pragma unroll
    for (int t = 0; t < 8; ++t) {
        const int col = t * 16 + colb;
        float badd = bias[col];
        if (L2E) badd = fmaf(ns, shW2[col], badd);
        float s = 0.f, q = 0.f;
#pragma unroll
        for (int j = 0; j < 4; ++j) {
            const float y = fmaxf(acc[t][j] + badd, 0.f);
            const size_t r = (size_t)(row0 + rbase + j);
            if (L2E) ((float*)Yout)[r * 128 + col] = y;
            else ((unsigned short*)Yout)[r * 128 + col] = (unsigned short)f2bf(y);
            s += y; q = fmaf(y, y, q);
        }
        atomicAdd(&lsum[col], s);
        atomicAdd(&lsq[col], q);
    }
    __syncthreads();
    if (tid < 128) { atomicAdd(&gsum[tid], lsum[tid]); atomicAdd(&gsq[tid], lsq[tid]); }
}

// ---------------------------------------------------------------------------
// K8: BN finalize -> per-channel scale/shift
__global__ void k_bnfin(const float* __restrict__ gsum, const float* __restrict__ gsq,
                        const float* __restrict__ gamma, const float* __restrict__ beta,
                        float* __restrict__ scale, float* __restrict__ shift) {
    const int c = threadIdx.x;
    const float inv = 1.0f / (float)(Bb * Nn);
    const float mu  = gsum[c] * inv;
    const float var = gsq[c] * inv - mu * mu;
    const float s   = gamma[c] * rsqrtf(var + BN_EPS);
    scale[c] = s;
    shift[c] = beta[c] - mu * s;
}

// ---------------------------------------------------------------------------
// K9: classifier. Rows node-major (r = n*4+b); out[b*Nn+n].
__global__ __launch_bounds__(256) void k_cls(const float* __restrict__ Hin,
                                             const float* __restrict__ scale,
                                             const float* __restrict__ shift,
                                             const float* __restrict__ Wc,
                                             const float* __restrict__ bc,
                                             float* __restrict__ out) {
    const int wave = threadIdx.x >> 6;
    const int lane = threadIdx.x & 63;
    const size_t row = (size_t)blockIdx.x * 4 + wave;
    if (row >= (size_t)Bb * Nn) return;
    const int c0 = lane * 2;
    const float2 h = *(const float2*)(Hin + row * Hh + c0);
    float p = (h.x * scale[c0] + shift[c0]) * Wc[c0] +
              (h.y * scale[c0 + 1] + shift[c0 + 1]) * Wc[c0 + 1];
#pragma unroll
    for (int off = 32; off; off >>= 1) p += __shfl_down(p, off);
    if (lane == 0) {
        const int n = (int)(row >> 2), b = (int)(row & 3);
        out[(size_t)b * Nn + n] = p + bc[0];
    }
}

// ---------------------------------------------------------------------------
extern "C" void kernel_launch(void* const* d_in, const int* in_sizes, int n_in,
                              void* d_out, int out_size, void* d_ws, size_t ws_size,
                              hipStream_t stream) {
    const float* x      = (const float*)d_in[0];
    const int*   ei     = (const int*)d_in[1];
    const float* W1     = (const float*)d_in[2];
    const float* b1     = (const float*)d_in[3];
    const float* W2     = (const float*)d_in[4];
    const float* b2     = (const float*)d_in[5];
    const float* gamma1 = (const float*)d_in[6];
    const float* beta1  = (const float*)d_in[7];
    const float* gamma2 = (const float*)d_in[8];
    const float* beta2  = (const float*)d_in[9];
    const float* Wc     = (const float*)d_in[10];
    const float* bc     = (const float*)d_in[11];
    float* out = (float*)d_out;

    const int E = in_sizes[1] / 2;
    const int* src = ei;
    const int* dst = ei + E;

    char* ws = (char*)d_ws;
    size_t off = 0;
    auto alloc = [&](size_t bytes) -> char* {
        char* p = ws + off;
        off += (bytes + 255) & ~(size_t)255;
        return p;
    };
    int*      deg      = (int*)     alloc((size_t)Nn * 4);
    int*      cursor   = (int*)     alloc((size_t)Nn * 4);
    int*      rowptr   = (int*)     alloc((size_t)(Nn + 1) * 4);
    float*    dinv     = (float*)   alloc((size_t)Nn * 4);
    float*    nsum     = (float*)   alloc((size_t)Nn * 4);
    int*      csr_src  = (int*)     alloc((size_t)(E + Nn) * 4);
    float*    csr_norm = (float*)   alloc((size_t)(E + Nn) * 4);
    float*    stats    = (float*)   alloc((size_t)8 * Hh * 4);
    float* gsum1 = stats,           *gsq1 = stats + Hh;
    float* scale1 = stats + 2 * Hh, *shift1 = stats + 3 * Hh;
    float* gsum2 = stats + 4 * Hh,  *gsq2 = stats + 5 * Hh;
    float* scale2 = stats + 6 * Hh, *shift2 = stats + 7 * Hh;
    unsigned short* WT1  = (unsigned short*)alloc((size_t)128 * Ff * 2);
    unsigned short* WT2  = (unsigned short*)alloc((size_t)128 * Hh * 2);
    float*          shW2 = (float*)         alloc((size_t)128 * 4);
    unsigned*       xb    = (unsigned*)      alloc((size_t)Nn * Bb * 32 * 4);  // bf16 x node-major
    unsigned short* aggXb = (unsigned short*)alloc((size_t)Bb * Nn * Ff * 2);  // bf16 [80000][64]
    unsigned short* h1b   = (unsigned short*)alloc((size_t)Bb * Nn * Hh * 2);  // bf16 [80000][128]
    unsigned short* aggHb = (unsigned short*)alloc((size_t)Bb * Nn * Hh * 2);  // bf16 [80000][128]
    float*          bufB  = (float*)         alloc((size_t)Bb * Nn * Hh * 4);  // fp32 conv2-out

    (void)hipMemsetAsync(deg, 0, (size_t)Nn * 4, stream);
    (void)hipMemsetAsync(nsum, 0, (size_t)Nn * 4, stream);
    (void)hipMemsetAsync(gsum1, 0, (size_t)2 * Hh * 4, stream);
    (void)hipMemsetAsync(gsum2, 0, (size_t)2 * Hh * 4, stream);

    k_deg<<<(E + 255) / 256, 256, 0, stream>>>(dst, E, deg);
    k_scan<<<1, 1024, 0, stream>>>(deg, rowptr, cursor, dinv);
    k_fill<<<(E + Nn + 255) / 256, 256, 0, stream>>>(src, dst, E, dinv, cursor,
                                                     csr_src, csr_norm, nsum);
    k_cvt<<<(Bb * Nn * 32 + 255) / 256, 256, 0, stream>>>(x, xb);
    k_wt<Ff, false><<<(128 * Ff) / 256, 256, 0, stream>>>(W1, nullptr, WT1);

    // Layer 1: agg(x) @ W1  (+b1, ReLU, BN1 stats, bf16 out)
    k_agg1<<<(Nn + 3) / 4, 256, 0, stream>>>(xb, rowptr, csr_src, csr_norm, aggXb);
    k_mm<Ff, false><<<(Bb * Nn) / 64, 256, 0, stream>>>(
        aggXb, WT1, b1, nullptr, nullptr, h1b, gsum1, gsq1);
    k_bnfin<<<1, Hh, 0, stream>>>(gsum1, gsq1, gamma1, beta1, scale1, shift1);

    // Layer 2: agg(h1) @ (sc1.W2) + nsum*(sh1@W2) + b2, ReLU, BN2 stats, fp32 out
    k_wt<Hh, true><<<(128 * Hh) / 256, 256, 0, stream>>>(W2, scale1, WT2);
    k_shw<<<1, Hh, 0, stream>>>(shift1, W2, shW2);
    k_agg2<<<(Nn + 3) / 4, 256, 0, stream>>>((const unsigned*)h1b, rowptr, csr_src,
                                             csr_norm, aggHb);
    k_mm<Hh, true><<<(Bb * Nn) / 64, 256, 0, stream>>>(
        aggHb, WT2, b2, nsum, shW2, bufB, gsum2, gsq2);
    k_bnfin<<<1, Hh, 0, stream>>>(gsum2, gsq2, gamma2, beta2, scale2, shift2);

    // Classifier (BN2 inline)
    k_cls<<<(Bb * Nn + 3) / 4, 256, 0, stream>>>(bufB, scale2, shift2, Wc, bc, out);
}

// Round 6
// 257.290 us; speedup vs baseline: 2.6125x; 1.1608x over previous
//
#include <hip/hip_runtime.h>

// Problem constants (fixed by setup_inputs)
constexpr int Bb = 4;
constexpr int Nn = 20000;
constexpr int Ff = 64;
constexpr int Hh = 128;
constexpr float BN_EPS = 1e-5f;
constexpr int NSLOTS = 64;   // BN-stat atomic spread (blockIdx & 63)

typedef __attribute__((ext_vector_type(8))) short bf16x8;
typedef __attribute__((ext_vector_type(4))) float f32x4;

// bf16 helpers (RNE pack, cheap unpack)
__device__ inline unsigned f2bf(float f) {
    unsigned u = __float_as_uint(f);
    return (u + 0x7fffu + ((u >> 16) & 1u)) >> 16;
}
__device__ inline unsigned pack2(float lo, float hi) { return f2bf(lo) | (f2bf(hi) << 16); }
__device__ inline float bf_lo(unsigned w) { return __uint_as_float(w << 16); }
__device__ inline float bf_hi(unsigned w) { return __uint_as_float(w & 0xffff0000u); }

// ---------------------------------------------------------------------------
// K1: degree count over dst
__global__ void k_deg(const int* __restrict__ dst, int E, int* __restrict__ deg) {
    int e = blockIdx.x * blockDim.x + threadIdx.x;
    if (e < E) atomicAdd(&deg[dst[e]], 1);
}

// ---------------------------------------------------------------------------
// K2: single-block scan over (deg[v]+1) -> rowptr, cursor, dinv.
// shfl-based per-wave scan + cross-wave LDS: 3 barriers/tile (old: ~20).
__global__ __launch_bounds__(1024) void k_scan(const int* __restrict__ deg,
                                               int* __restrict__ rowptr,
                                               int* __restrict__ cursor,
                                               float* __restrict__ dinv) {
    __shared__ int wsum[16];
    __shared__ int carry_s, tsum_s;
    const int tid = threadIdx.x;
    const int lane = tid & 63, wid = tid >> 6;
    if (tid == 0) carry_s = 0;
    __syncthreads();
    for (int base = 0; base < Nn; base += 1024) {
        const int i = base + tid;
        const int cnt = (i < Nn) ? (deg[i] + 1) : 0;  // +1 = self loop
        int v = cnt;
#pragma unroll
        for (int d = 1; d < 64; d <<= 1) {
            const int t = __shfl_up(v, d);
            if (lane >= d) v += t;
        }                                    // v = inclusive scan within wave
        if (lane == 63) wsum[wid] = v;
        __syncthreads();                     // B1
        if (wid == 0) {
            const int orig = (lane < 16) ? wsum[lane] : 0;
            int w = orig;
#pragma unroll
            for (int d = 1; d < 16; d <<= 1) {
                const int t = __shfl_up(w, d);
                if (lane >= d) w += t;
            }
            if (lane == 15) tsum_s = w;      // tile total
            if (lane < 16) wsum[lane] = w - orig;  // exclusive wave offsets
        }
        __syncthreads();                     // B2
        const int c = carry_s;
        const int excl = c + wsum[wid] + (v - cnt);
        if (i < Nn) {
            rowptr[i] = excl;
            cursor[i] = excl;
            dinv[i]   = rsqrtf((float)cnt);
        }
        __syncthreads();                     // B3 (all reads of carry_s/wsum done)
        if (tid == 0) carry_s += tsum_s;     // visible by next B2
    }
    if (tid == 0) rowptr[Nn] = carry_s;      // same thread as update: safe
}

// ---------------------------------------------------------------------------
// K3: fill CSR + per-edge norm + per-node nsum (= sum of norms, for BN-fold)
__global__ void k_fill(const int* __restrict__ src, const int* __restrict__ dst, int E,
                       const float* __restrict__ dinv, int* __restrict__ cursor,
                       int* __restrict__ csr_src, float* __restrict__ csr_norm,
                       float* __restrict__ nsum) {
    int t = blockIdx.x * blockDim.x + threadIdx.x;
    int s, d;
    if (t < E) { s = src[t]; d = dst[t]; }
    else if (t < E + Nn) { s = d = t - E; }
    else return;
    int pos = atomicAdd(&cursor[d], 1);
    const float nm = dinv[s] * dinv[d];
    csr_src[pos]  = s;
    csr_norm[pos] = nm;
    atomicAdd(&nsum[d], nm);
}

// ---------------------------------------------------------------------------
// K4: convert x [B][N][64] fp32 -> xb [N][B][64] bf16 (node-major interleave)
__global__ void k_cvt(const float* __restrict__ x, unsigned* __restrict__ xb) {
    const int t = blockIdx.x * 256 + threadIdx.x;   // enumerates B*N*32 uint outputs
    if (t >= Bb * Nn * 32) return;
    const int c2 = t & 31;
    const int bn = t >> 5;
    const int n  = bn % Nn;
    const int b  = bn / Nn;
    const float2 v = *(const float2*)&x[(size_t)t * 2];
    xb[((size_t)n * Bb + b) * 32 + c2] = pack2(v.x, v.y);
}

// ---------------------------------------------------------------------------
// K5: weight prep: WT[c][k] = bf16( (FOLD ? sc[k] : 1) * W[k][c] )  (transpose)
template <int K, bool FOLD>
__global__ void k_wt(const float* __restrict__ W, const float* __restrict__ sc,
                     unsigned short* __restrict__ WT) {
    const int t = blockIdx.x * 256 + threadIdx.x;
    if (t >= 128 * K) return;
    const int c = t / K, k = t % K;
    float v = W[(size_t)k * 128 + c];
    if (FOLD) v *= sc[k];
    WT[(size_t)c * K + k] = (unsigned short)f2bf(v);
}

// K5b: shW2[c] = sum_k sh[k] * W2[k][c]   (one block, 128 threads)
__global__ void k_shw(const float* __restrict__ sh, const float* __restrict__ W2,
                      float* __restrict__ shW2) {
    const int c = threadIdx.x;
    float s = 0.f;
    for (int k = 0; k < Hh; ++k) s = fmaf(sh[k], W2[(size_t)k * 128 + c], s);
    shW2[c] = s;
}

// ---------------------------------------------------------------------------
// K6a: aggregate xb (64ch bf16, node-major) -> aggXb bf16 [80000][64]
__global__ __launch_bounds__(256) void k_agg1(const unsigned* __restrict__ xb,
                                              const int* __restrict__ rowptr,
                                              const int* __restrict__ csr_src,
                                              const float* __restrict__ csr_norm,
                                              unsigned short* __restrict__ aggXb) {
    const int wave = threadIdx.x >> 6, lane = threadIdx.x & 63;
    const int v = blockIdx.x * 4 + wave;
    if (v >= Nn) return;
    const int beg = rowptr[v], end = rowptr[v + 1];
    float a0 = 0.f, a1 = 0.f, a2 = 0.f, a3 = 0.f;
    int e = beg;
    for (; e + 4 <= end; e += 4) {
        const int s0 = csr_src[e], s1 = csr_src[e + 1], s2 = csr_src[e + 2], s3 = csr_src[e + 3];
        const uint2 w0 = *(const uint2*)(xb + (size_t)s0 * 128 + lane * 2);
        const uint2 w1 = *(const uint2*)(xb + (size_t)s1 * 128 + lane * 2);
        const uint2 w2 = *(const uint2*)(xb + (size_t)s2 * 128 + lane * 2);
        const uint2 w3 = *(const uint2*)(xb + (size_t)s3 * 128 + lane * 2);
        const float n0 = csr_norm[e], n1 = csr_norm[e + 1], n2 = csr_norm[e + 2], n3 = csr_norm[e + 3];
        a0 = fmaf(n0, bf_lo(w0.x), a0); a1 = fmaf(n0, bf_hi(w0.x), a1);
        a2 = fmaf(n0, bf_lo(w0.y), a2); a3 = fmaf(n0, bf_hi(w0.y), a3);
        a0 = fmaf(n1, bf_lo(w1.x), a0); a1 = fmaf(n1, bf_hi(w1.x), a1);
        a2 = fmaf(n1, bf_lo(w1.y), a2); a3 = fmaf(n1, bf_hi(w1.y), a3);
        a0 = fmaf(n2, bf_lo(w2.x), a0); a1 = fmaf(n2, bf_hi(w2.x), a1);
        a2 = fmaf(n2, bf_lo(w2.y), a2); a3 = fmaf(n2, bf_hi(w2.y), a3);
        a0 = fmaf(n3, bf_lo(w3.x), a0); a1 = fmaf(n3, bf_hi(w3.x), a1);
        a2 = fmaf(n3, bf_lo(w3.y), a2); a3 = fmaf(n3, bf_hi(w3.y), a3);
    }
    for (; e < end; ++e) {
        const int s = csr_src[e];
        const float nm = csr_norm[e];
        const uint2 w = *(const uint2*)(xb + (size_t)s * 128 + lane * 2);
        a0 = fmaf(nm, bf_lo(w.x), a0); a1 = fmaf(nm, bf_hi(w.x), a1);
        a2 = fmaf(nm, bf_lo(w.y), a2); a3 = fmaf(nm, bf_hi(w.y), a3);
    }
    unsigned short* o = aggXb + ((size_t)v * 4 + (lane >> 4)) * 64 + (lane & 15) * 4;
    *(uint2*)o = make_uint2(pack2(a0, a1), pack2(a2, a3));
}

// ---------------------------------------------------------------------------
// K6b: aggregate hb (128ch bf16, node-major) -> aggHb bf16 [80000][128]
__global__ __launch_bounds__(256) void k_agg2(const unsigned* __restrict__ hb,
                                              const int* __restrict__ rowptr,
                                              const int* __restrict__ csr_src,
                                              const float* __restrict__ csr_norm,
                                              unsigned short* __restrict__ aggHb) {
    const int wave = threadIdx.x >> 6, lane = threadIdx.x & 63;
    const int v = blockIdx.x * 4 + wave;
    if (v >= Nn) return;
    const int beg = rowptr[v], end = rowptr[v + 1];
    float a[8];
#pragma unroll
    for (int j = 0; j < 8; ++j) a[j] = 0.f;
    int e = beg;
    for (; e + 4 <= end; e += 4) {
        const int s0 = csr_src[e], s1 = csr_src[e + 1], s2 = csr_src[e + 2], s3 = csr_src[e + 3];
        const uint4 w0 = *(const uint4*)(hb + (size_t)s0 * 256 + lane * 4);
        const uint4 w1 = *(const uint4*)(hb + (size_t)s1 * 256 + lane * 4);
        const uint4 w2 = *(const uint4*)(hb + (size_t)s2 * 256 + lane * 4);
        const uint4 w3 = *(const uint4*)(hb + (size_t)s3 * 256 + lane * 4);
        const float n0 = csr_norm[e], n1 = csr_norm[e + 1], n2 = csr_norm[e + 2], n3 = csr_norm[e + 3];
        a[0] = fmaf(n0, bf_lo(w0.x), a[0]); a[1] = fmaf(n0, bf_hi(w0.x), a[1]);
        a[2] = fmaf(n0, bf_lo(w0.y), a[2]); a[3] = fmaf(n0, bf_hi(w0.y), a[3]);
        a[4] = fmaf(n0, bf_lo(w0.z), a[4]); a[5] = fmaf(n0, bf_hi(w0.z), a[5]);
        a[6] = fmaf(n0, bf_lo(w0.w), a[6]); a[7] = fmaf(n0, bf_hi(w0.w), a[7]);
        a[0] = fmaf(n1, bf_lo(w1.x), a[0]); a[1] = fmaf(n1, bf_hi(w1.x), a[1]);
        a[2] = fmaf(n1, bf_lo(w1.y), a[2]); a[3] = fmaf(n1, bf_hi(w1.y), a[3]);
        a[4] = fmaf(n1, bf_lo(w1.z), a[4]); a[5] = fmaf(n1, bf_hi(w1.z), a[5]);
        a[6] = fmaf(n1, bf_lo(w1.w), a[6]); a[7] = fmaf(n1, bf_hi(w1.w), a[7]);
        a[0] = fmaf(n2, bf_lo(w2.x), a[0]); a[1] = fmaf(n2, bf_hi(w2.x), a[1]);
        a[2] = fmaf(n2, bf_lo(w2.y), a[2]); a[3] = fmaf(n2, bf_hi(w2.y), a[3]);
        a[4] = fmaf(n2, bf_lo(w2.z), a[4]); a[5] = fmaf(n2, bf_hi(w2.z), a[5]);
        a[6] = fmaf(n2, bf_lo(w2.w), a[6]); a[7] = fmaf(n2, bf_hi(w2.w), a[7]);
        a[0] = fmaf(n3, bf_lo(w3.x), a[0]); a[1] = fmaf(n3, bf_hi(w3.x), a[1]);
        a[2] = fmaf(n3, bf_lo(w3.y), a[2]); a[3] = fmaf(n3, bf_hi(w3.y), a[3]);
        a[4] = fmaf(n3, bf_lo(w3.z), a[4]); a[5] = fmaf(n3, bf_hi(w3.z), a[5]);
        a[6] = fmaf(n3, bf_lo(w3.w), a[6]); a[7] = fmaf(n3, bf_hi(w3.w), a[7]);
    }
    for (; e < end; ++e) {
        const int s = csr_src[e];
        const float nm = csr_norm[e];
        const uint4 w = *(const uint4*)(hb + (size_t)s * 256 + lane * 4);
        a[0] = fmaf(nm, bf_lo(w.x), a[0]); a[1] = fmaf(nm, bf_hi(w.x), a[1]);
        a[2] = fmaf(nm, bf_lo(w.y), a[2]); a[3] = fmaf(nm, bf_hi(w.y), a[3]);
        a[4] = fmaf(nm, bf_lo(w.z), a[4]); a[5] = fmaf(nm, bf_hi(w.z), a[5]);
        a[6] = fmaf(nm, bf_lo(w.w), a[6]); a[7] = fmaf(nm, bf_hi(w.w), a[7]);
    }
    unsigned short* o = aggHb + ((size_t)v * 4 + (lane >> 4)) * 128 + (lane & 15) * 8;
    *(uint4*)o = make_uint4(pack2(a[0], a[1]), pack2(a[2], a[3]),
                            pack2(a[4], a[5]), pack2(a[6], a[7]));
}

// ---------------------------------------------------------------------------
// K7: MFMA GEMM. C[64rows x 128] = A[64 x K]_bf16 @ WT^T (WT is [128][K] bf16).
// BN-stat partial sums go to slot (blockIdx & 63) -> ~20 same-address RMWs
// instead of 1250 (R5: same-address atomic serialization was the ~30us floor).
template <int K, bool L2E>
__global__ __launch_bounds__(256) void k_mm(const unsigned short* __restrict__ A,
                                            const unsigned short* __restrict__ WT,
                                            const float* __restrict__ bias,
                                            const float* __restrict__ nsum,
                                            const float* __restrict__ shW2,
                                            unsigned short* __restrict__ Yout,
                                            float* __restrict__ gsum,
                                            float* __restrict__ gsq) {
    constexpr int NKS = K / 32;
    constexpr int AST = K + 8;
    constexpr int NSLOT = 8 * NKS * 64;
    __shared__ alignas(16) unsigned short sB[NSLOT * 8];
    __shared__ alignas(16) unsigned short sA[64 * AST];
    __shared__ float lsum[128], lsq[128];

    const int tid = threadIdx.x;
    const int row0 = blockIdx.x * 64;
    if (tid < 128) { lsum[tid] = 0.f; lsq[tid] = 0.f; }

#pragma unroll
    for (int i = 0; i < NSLOT / 256; ++i) {
        const int s = tid + i * 256;
        const int l = s & 63;
        const int ks = (s >> 6) % NKS;
        const int ct = (s >> 6) / NKS;
        const int col = ct * 16 + (l & 15);
        const int k = ks * 32 + ((l >> 4) << 3);
        *(uint4*)&sB[s * 8] = *(const uint4*)&WT[(size_t)col * K + k];
    }
#pragma unroll
    for (int i = 0; i < (64 * K / 8) / 256; ++i) {
        const int c = tid + i * 256;
        const int row = c / (K / 8);
        const int k8 = c % (K / 8);
        *(uint4*)&sA[row * AST + k8 * 8] = *(const uint4*)&A[(size_t)(row0 + row) * K + k8 * 8];
    }
    __syncthreads();

    const int w = tid >> 6, lane = tid & 63;
    const int rowL = w * 16 + (lane & 15);
    const int kg = lane >> 4;

    f32x4 acc[8];
#pragma unroll
    for (int t = 0; t < 8; ++t) acc[t] = (f32x4){0.f, 0.f, 0.f, 0.f};

#pragma unroll
    for (int ks = 0; ks < NKS; ++ks) {
        const bf16x8 a = *(const bf16x8*)&sA[rowL * AST + ks * 32 + kg * 8];
#pragma unroll
        for (int t = 0; t < 8; ++t) {
            const bf16x8 b = *(const bf16x8*)&sB[((t * NKS + ks) * 64 + lane) * 8];
            acc[t] = __builtin_amdgcn_mfma_f32_16x16x32_bf16(a, b, acc[t], 0, 0, 0);
        }
    }

    // epilogue: +bias (+ns*shW2 for L2E), ReLU, bf16 store, BN partial stats
    const int colb = lane & 15;
    const int rbase = w * 16 + kg * 4;        // 4 regs = 4 batches of ONE node
    float ns = 0.f;
    if (L2E) ns = nsum[(row0 + rbase) >> 2];
#pragma unroll
    for (int t = 0; t < 8; ++t) {
        const int col = t * 16 + colb;
        float badd = bias[col];
        if (L2E) badd = fmaf(ns, shW2[col], badd);
        float s = 0.f, q = 0.f;
#pragma unroll
        for (int j = 0; j < 4; ++j) {
            const float y = fmaxf(acc[t][j] + badd, 0.f);
            const size_t r = (size_t)(row0 + rbase + j);
            Yout[r * 128 + col] = (unsigned short)f2bf(y);
            s += y; q = fmaf(y, y, q);
        }
        atomicAdd(&lsum[col], s);
        atomicAdd(&lsq[col], q);
    }
    __syncthreads();
    float* gs = gsum + (size_t)(blockIdx.x & (NSLOTS - 1)) * 128;
    float* gq = gsq  + (size_t)(blockIdx.x & (NSLOTS - 1)) * 128;
    if (tid < 128) { atomicAdd(&gs[tid], lsum[tid]); atomicAdd(&gq[tid], lsq[tid]); }
}

// ---------------------------------------------------------------------------
// K8a: BN finalize (layer 1) -> scale/shift from 64-slot partials
__global__ void k_bnfin(const float* __restrict__ gsum, const float* __restrict__ gsq,
                        const float* __restrict__ gamma, const float* __restrict__ beta,
                        float* __restrict__ scale, float* __restrict__ shift) {
    const int c = threadIdx.x;
    float s = 0.f, q = 0.f;
    for (int j = 0; j < NSLOTS; ++j) { s += gsum[j * 128 + c]; q += gsq[j * 128 + c]; }
    const float inv = 1.0f / (float)(Bb * Nn);
    const float mu  = s * inv;
    const float var = q * inv - mu * mu;
    const float sc  = gamma[c] * rsqrtf(var + BN_EPS);
    scale[c] = sc;
    shift[c] = beta[c] - mu * sc;
}

// K8b: BN finalize (layer 2) folded into classifier weights:
//   wcs[c] = sc2[c]*Wc[c],  kc = sum_c sh2[c]*Wc[c] + bc
__global__ void k_bnfin2(const float* __restrict__ gsum, const float* __restrict__ gsq,
                         const float* __restrict__ gamma, const float* __restrict__ beta,
                         const float* __restrict__ Wc, const float* __restrict__ bc,
                         float* __restrict__ wcs, float* __restrict__ kc) {
    __shared__ float red[128];
    const int c = threadIdx.x;
    float s = 0.f, q = 0.f;
    for (int j = 0; j < NSLOTS; ++j) { s += gsum[j * 128 + c]; q += gsq[j * 128 + c]; }
    const float inv = 1.0f / (float)(Bb * Nn);
    const float mu  = s * inv;
    const float var = q * inv - mu * mu;
    const float sc  = gamma[c] * rsqrtf(var + BN_EPS);
    const float sh  = beta[c] - mu * sc;
    const float w   = Wc[c];
    wcs[c] = sc * w;
    red[c] = sh * w;
    __syncthreads();
    for (int st = 64; st; st >>= 1) {
        if (c < st) red[c] += red[c + st];
        __syncthreads();
    }
    if (c == 0) kc[0] = red[0] + bc[0];
}

// ---------------------------------------------------------------------------
// K9: classifier on bf16 h2: out[b*Nn+n] = sum_c h2[r][c]*wcs[c] + kc
__global__ __launch_bounds__(256) void k_cls(const unsigned* __restrict__ h2,
                                             const float* __restrict__ wcs,
                                             const float* __restrict__ kc,
                                             float* __restrict__ out) {
    const int wave = threadIdx.x >> 6;
    const int lane = threadIdx.x & 63;
    const size_t row = (size_t)blockIdx.x * 4 + wave;
    if (row >= (size_t)Bb * Nn) return;
    const unsigned w = h2[row * 64 + lane];          // 2 channels
    const float2 wc = *(const float2*)&wcs[lane * 2];
    float p = bf_lo(w) * wc.x + bf_hi(w) * wc.y;
#pragma unroll
    for (int off = 32; off; off >>= 1) p += __shfl_down(p, off);
    if (lane == 0) {
        const int n = (int)(row >> 2), b = (int)(row & 3);
        out[(size_t)b * Nn + n] = p + kc[0];
    }
}

// ---------------------------------------------------------------------------
extern "C" void kernel_launch(void* const* d_in, const int* in_sizes, int n_in,
                              void* d_out, int out_size, void* d_ws, size_t ws_size,
                              hipStream_t stream) {
    const float* x      = (const float*)d_in[0];
    const int*   ei     = (const int*)d_in[1];
    const float* W1     = (const float*)d_in[2];
    const float* b1     = (const float*)d_in[3];
    const float* W2     = (const float*)d_in[4];
    const float* b2     = (const float*)d_in[5];
    const float* gamma1 = (const float*)d_in[6];
    const float* beta1  = (const float*)d_in[7];
    const float* gamma2 = (const float*)d_in[8];
    const float* beta2  = (const float*)d_in[9];
    const float* Wc     = (const float*)d_in[10];
    const float* bc     = (const float*)d_in[11];
    float* out = (float*)d_out;

    const int E = in_sizes[1] / 2;
    const int* src = ei;
    const int* dst = ei + E;

    char* ws = (char*)d_ws;
    size_t off = 0;
    auto alloc = [&](size_t bytes) -> char* {
        char* p = ws + off;
        off += (bytes + 255) & ~(size_t)255;
        return p;
    };
    int*      deg      = (int*)     alloc((size_t)Nn * 4);
    int*      cursor   = (int*)     alloc((size_t)Nn * 4);
    int*      rowptr   = (int*)     alloc((size_t)(Nn + 1) * 4);
    float*    dinv     = (float*)   alloc((size_t)Nn * 4);
    float*    nsum     = (float*)   alloc((size_t)Nn * 4);
    int*      csr_src  = (int*)     alloc((size_t)(E + Nn) * 4);
    float*    csr_norm = (float*)   alloc((size_t)(E + Nn) * 4);
    float*    gstat    = (float*)   alloc((size_t)4 * NSLOTS * 128 * 4);  // 128KB
    float* gsum1 = gstat;
    float* gsq1  = gstat + NSLOTS * 128;
    float* gsum2 = gstat + 2 * NSLOTS * 128;
    float* gsq2  = gstat + 3 * NSLOTS * 128;
    float*    scale1 = (float*)alloc(128 * 4);
    float*    shift1 = (float*)alloc(128 * 4);
    float*    wcs    = (float*)alloc(128 * 4);
    float*    kc     = (float*)alloc(256);
    unsigned short* WT1  = (unsigned short*)alloc((size_t)128 * Ff * 2);
    unsigned short* WT2  = (unsigned short*)alloc((size_t)128 * Hh * 2);
    float*          shW2 = (float*)         alloc((size_t)128 * 4);
    unsigned*       xb    = (unsigned*)      alloc((size_t)Nn * Bb * 32 * 4);  // bf16 x node-major
    unsigned short* aggXb = (unsigned short*)alloc((size_t)Bb * Nn * Ff * 2);  // bf16 [80000][64]
    unsigned short* h1b   = (unsigned short*)alloc((size_t)Bb * Nn * Hh * 2);  // bf16 [80000][128]
    unsigned short* aggHb = (unsigned short*)alloc((size_t)Bb * Nn * Hh * 2);  // bf16 [80000][128]
    unsigned short* h2b   = (unsigned short*)alloc((size_t)Bb * Nn * Hh * 2);  // bf16 [80000][128]

    (void)hipMemsetAsync(deg, 0, (size_t)Nn * 4, stream);
    (void)hipMemsetAsync(nsum, 0, (size_t)Nn * 4, stream);
    (void)hipMemsetAsync(gstat, 0, (size_t)4 * NSLOTS * 128 * 4, stream);

    k_deg<<<(E + 255) / 256, 256, 0, stream>>>(dst, E, deg);
    k_scan<<<1, 1024, 0, stream>>>(deg, rowptr, cursor, dinv);
    k_fill<<<(E + Nn + 255) / 256, 256, 0, stream>>>(src, dst, E, dinv, cursor,
                                                     csr_src, csr_norm, nsum);
    k_cvt<<<(Bb * Nn * 32 + 255) / 256, 256, 0, stream>>>(x, xb);
    k_wt<Ff, false><<<(128 * Ff) / 256, 256, 0, stream>>>(W1, nullptr, WT1);

    // Layer 1: agg(x) @ W1  (+b1, ReLU, BN1 stats, bf16 out)
    k_agg1<<<(Nn + 3) / 4, 256, 0, stream>>>(xb, rowptr, csr_src, csr_norm, aggXb);
    k_mm<Ff, false><<<(Bb * Nn) / 64, 256, 0, stream>>>(
        aggXb, WT1, b1, nullptr, nullptr, h1b, gsum1, gsq1);
    k_bnfin<<<1, Hh, 0, stream>>>(gsum1, gsq1, gamma1, beta1, scale1, shift1);

    // Layer 2: agg(h1) @ (sc1.W2) + nsum*(sh1@W2) + b2, ReLU, BN2 stats, bf16 out
    k_wt<Hh, true><<<(128 * Hh) / 256, 256, 0, stream>>>(W2, scale1, WT2);
    k_shw<<<1, Hh, 0, stream>>>(shift1, W2, shW2);
    k_agg2<<<(Nn + 3) / 4, 256, 0, stream>>>((const unsigned*)h1b, rowptr, csr_src,
                                             csr_norm, aggHb);
    k_mm<Hh, true><<<(Bb * Nn) / 64, 256, 0, stream>>>(
        aggHb, WT2, b2, nsum, shW2, h2b, gsum2, gsq2);
    k_bnfin2<<<1, Hh, 0, stream>>>(gsum2, gsq2, gamma2, beta2, Wc, bc, wcs, kc);

    // Classifier (BN2 folded into wcs/kc)
    k_cls<<<(Bb * Nn + 3) / 4, 256, 0, stream>>>((const unsigned*)h2b, wcs, kc, out);
}

// Round 7
// 233.557 us; speedup vs baseline: 2.8780x; 1.1016x over previous
//
#include <hip/hip_runtime.h>

// Problem constants (fixed by setup_inputs)
constexpr int Bb = 4;
constexpr int Nn = 20000;
constexpr int Ff = 64;
constexpr int Hh = 128;
constexpr float BN_EPS = 1e-5f;
constexpr int NSLOTS = 64;               // BN-stat atomic spread (blockIdx & 63)
constexpr int NB = (Nn + 1023) / 1024;   // scan blocks (20)

typedef __attribute__((ext_vector_type(8))) short bf16x8;
typedef __attribute__((ext_vector_type(4))) float f32x4;

// bf16 helpers (RNE pack, cheap unpack)
__device__ inline unsigned f2bf(float f) {
    unsigned u = __float_as_uint(f);
    return (u + 0x7fffu + ((u >> 16) & 1u)) >> 16;
}
__device__ inline unsigned pack2(float lo, float hi) { return f2bf(lo) | (f2bf(hi) << 16); }
__device__ inline float bf_lo(unsigned w) { return __uint_as_float(w << 16); }
__device__ inline float bf_hi(unsigned w) { return __uint_as_float(w & 0xffff0000u); }

template <int NU>
__device__ inline void ldrow(unsigned* u, const unsigned* p) {
    if constexpr (NU == 2) { const uint2 t = *(const uint2*)p; u[0] = t.x; u[1] = t.y; }
    else { const uint4 t = *(const uint4*)p; u[0] = t.x; u[1] = t.y; u[2] = t.z; u[3] = t.w; }
}
template <int NU>
__device__ inline void acc_row(float* a, const unsigned* u, float nm) {
#pragma unroll
    for (int c = 0; c < NU; ++c) {
        a[2 * c]     = fmaf(nm, bf_lo(u[c]), a[2 * c]);
        a[2 * c + 1] = fmaf(nm, bf_hi(u[c]), a[2 * c + 1]);
    }
}

// ---------------------------------------------------------------------------
// K1: degree count over dst
__global__ void k_deg(const int* __restrict__ dst, int E, int* __restrict__ deg) {
    int e = blockIdx.x * blockDim.x + threadIdx.x;
    if (e < E) atomicAdd(&deg[dst[e]], 1);
}

// ---------------------------------------------------------------------------
// K2: multi-block scan over (deg+1). scan1: block-local excl -> rowptr, block
// totals -> bsum. scan2: exclusive-scan bsum (1 block). scan3: add offsets,
// write rowptr/cursor/dinv (+rowptr[Nn]).
__global__ __launch_bounds__(1024) void k_scan1(const int* __restrict__ deg,
                                                int* __restrict__ rowptr,
                                                int* __restrict__ bsum) {
    __shared__ int wsum[16];
    const int tid = threadIdx.x, lane = tid & 63, wid = tid >> 6;
    const int i = blockIdx.x * 1024 + tid;
    const int cnt = (i < Nn) ? (deg[i] + 1) : 0;
    int v = cnt;
#pragma unroll
    for (int d = 1; d < 64; d <<= 1) {
        const int t = __shfl_up(v, d);
        if (lane >= d) v += t;
    }
    if (lane == 63) wsum[wid] = v;
    __syncthreads();
    if (wid == 0) {
        const int orig = (lane < 16) ? wsum[lane] : 0;
        int w = orig;
#pragma unroll
        for (int d = 1; d < 16; d <<= 1) {
            const int t = __shfl_up(w, d);
            if (lane >= d) w += t;
        }
        if (lane == 15) bsum[blockIdx.x] = w;
        if (lane < 16) wsum[lane] = w - orig;
    }
    __syncthreads();
    if (i < Nn) rowptr[i] = wsum[wid] + (v - cnt);   // block-local exclusive
}

__global__ void k_scan2(int* __restrict__ bsum) {
    const int lane = threadIdx.x;                    // 64 threads, 1 block
    const int v = (lane < NB) ? bsum[lane] : 0;
    int s = v;
#pragma unroll
    for (int d = 1; d < 64; d <<= 1) {
        const int t = __shfl_up(s, d);
        if (lane >= d) s += t;
    }
    if (lane < NB) bsum[lane] = s - v;               // exclusive
}

__global__ __launch_bounds__(1024) void k_scan3(const int* __restrict__ deg,
                                                int* __restrict__ rowptr,
                                                const int* __restrict__ bsum,
                                                int* __restrict__ cursor,
                                                float* __restrict__ dinv) {
    const int i = blockIdx.x * 1024 + threadIdx.x;
    if (i >= Nn) return;
    const int cnt = deg[i] + 1;
    const int excl = rowptr[i] + bsum[blockIdx.x];
    rowptr[i] = excl;
    cursor[i] = excl;
    dinv[i] = rsqrtf((float)cnt);
    if (i == Nn - 1) rowptr[Nn] = excl + cnt;
}

// ---------------------------------------------------------------------------
// K3: fill CSR + per-edge norm + per-node nsum (= sum of norms, for BN-fold)
__global__ void k_fill(const int* __restrict__ src, const int* __restrict__ dst, int E,
                       const float* __restrict__ dinv, int* __restrict__ cursor,
                       int* __restrict__ csr_src, float* __restrict__ csr_norm,
                       float* __restrict__ nsum) {
    int t = blockIdx.x * blockDim.x + threadIdx.x;
    int s, d;
    if (t < E) { s = src[t]; d = dst[t]; }
    else if (t < E + Nn) { s = d = t - E; }
    else return;
    int pos = atomicAdd(&cursor[d], 1);
    const float nm = dinv[s] * dinv[d];
    csr_src[pos]  = s;
    csr_norm[pos] = nm;
    atomicAdd(&nsum[d], nm);
}

// ---------------------------------------------------------------------------
// K4: convert x [B][N][64] fp32 -> xb [N][B][64] bf16 (node-major interleave)
__global__ void k_cvt(const float* __restrict__ x, unsigned* __restrict__ xb) {
    const int t = blockIdx.x * 256 + threadIdx.x;   // enumerates B*N*32 uint outputs
    if (t >= Bb * Nn * 32) return;
    const int c2 = t & 31;
    const int bn = t >> 5;
    const int n  = bn % Nn;
    const int b  = bn / Nn;
    const float2 v = *(const float2*)&x[(size_t)t * 2];
    xb[((size_t)n * Bb + b) * 32 + c2] = pack2(v.x, v.y);
}

// ---------------------------------------------------------------------------
// K5: weight prep (layer 1): WT[c][k] = bf16(W[k][c])
__global__ void k_wt1(const float* __restrict__ W, unsigned short* __restrict__ WT) {
    const int t = blockIdx.x * 256 + threadIdx.x;
    if (t >= 128 * Ff) return;
    const int c = t / Ff, k = t % Ff;
    WT[(size_t)c * Ff + k] = (unsigned short)f2bf(W[(size_t)k * 128 + c]);
}

// ---------------------------------------------------------------------------
// K6: fused BN1-finalize + WT2 fold + shW2. Every block redundantly reduces
// the 64-slot stats (cheap); blocks 0..63 write WT2 slices, block 64 shW2.
__global__ __launch_bounds__(128) void k_prep2(const float* __restrict__ gsum,
                                               const float* __restrict__ gsq,
                                               const float* __restrict__ gamma,
                                               const float* __restrict__ beta,
                                               const float* __restrict__ W2,
                                               unsigned short* __restrict__ WT2,
                                               float* __restrict__ shW2) {
    __shared__ float sc_s[128], sh_s[128];
    const int c = threadIdx.x;
    float s = 0.f, q = 0.f;
    for (int j = 0; j < NSLOTS; ++j) { s += gsum[j * 128 + c]; q += gsq[j * 128 + c]; }
    const float inv = 1.0f / (float)(Bb * Nn);
    const float mu  = s * inv;
    const float var = q * inv - mu * mu;
    const float sc  = gamma[c] * rsqrtf(var + BN_EPS);
    sc_s[c] = sc;
    sh_s[c] = beta[c] - mu * sc;
    __syncthreads();
    if (blockIdx.x < 64) {
#pragma unroll
        for (int i = 0; i < 2; ++i) {
            const int t = blockIdx.x * 256 + i * 128 + c;
            const int c2 = t >> 7, k = t & 127;
            WT2[(size_t)c2 * 128 + k] = (unsigned short)f2bf(sc_s[k] * W2[(size_t)k * 128 + c2]);
        }
    } else {
        float a = 0.f;
        for (int k = 0; k < 128; ++k) a = fmaf(sh_s[k], W2[(size_t)k * 128 + c], a);
        shW2[c] = a;
    }
}

// ---------------------------------------------------------------------------
// K7: FUSED gather-aggregate + MFMA GEMM.
// Block = 16 nodes = 64 rows. Wave w aggregates nodes blockIdx*16+w*4..+3 from
// node-major bf16 G ([N][B][K]) into fp32 regs, packs bf16 into LDS A-tile,
// then C[64x128] = A @ WT^T via mfma_f32_16x16x32_bf16 (frag-linear sB).
// Epilogue: +bias (+ns*shW2 if L2E), ReLU, bf16 store, slotted BN stats.
template <int K, bool L2E>
__global__ __launch_bounds__(256) void k_fmm(const unsigned* __restrict__ G,
                                             const int* __restrict__ rowptr,
                                             const int* __restrict__ csr_src,
                                             const float* __restrict__ csr_norm,
                                             const unsigned short* __restrict__ WT,
                                             const float* __restrict__ bias,
                                             const float* __restrict__ nsum,
                                             const float* __restrict__ shW2,
                                             unsigned short* __restrict__ Yout,
                                             float* __restrict__ gsum,
                                             float* __restrict__ gsq) {
    constexpr int NKS = K / 32;
    constexpr int AST = K + 8;
    constexpr int NSLOT = 8 * NKS * 64;
    constexpr int NU = K / 32;        // uints per lane per edge (2 or 4)
    constexpr int ROWU = Bb * K / 2;  // uints per node row (128 or 256)
    __shared__ alignas(16) unsigned short sB[NSLOT * 8];
    __shared__ alignas(16) unsigned short sA[64 * AST];
    __shared__ float lsum[128], lsq[128];

    const int tid = threadIdx.x;
    const int row0 = blockIdx.x * 64;
    if (tid < 128) { lsum[tid] = 0.f; lsq[tid] = 0.f; }

    // stage WT (frag-linear: slot s -> (coltile, kstep, lane) 16B)
#pragma unroll
    for (int i = 0; i < NSLOT / 256; ++i) {
        const int s = tid + i * 256;
        const int l = s & 63;
        const int ks = (s >> 6) % NKS;
        const int ct = (s >> 6) / NKS;
        const int col = ct * 16 + (l & 15);
        const int k = ks * 32 + ((l >> 4) << 3);
        *(uint4*)&sB[s * 8] = *(const uint4*)&WT[(size_t)col * K + k];
    }

    // fused aggregation
    const int w = tid >> 6, lane = tid & 63;
    const int cg = lane & 15;
    for (int j = 0; j < 4; ++j) {
        const int v = blockIdx.x * 16 + w * 4 + j;
        const int beg = rowptr[v], end = rowptr[v + 1];
        float a[2 * NU];
#pragma unroll
        for (int c = 0; c < 2 * NU; ++c) a[c] = 0.f;
        int e = beg;
        for (; e + 4 <= end; e += 4) {
            const int s0 = csr_src[e],     s1 = csr_src[e + 1];
            const int s2 = csr_src[e + 2], s3 = csr_src[e + 3];
            unsigned u0[NU], u1[NU], u2[NU], u3[NU];
            ldrow<NU>(u0, G + (size_t)s0 * ROWU + lane * NU);
            ldrow<NU>(u1, G + (size_t)s1 * ROWU + lane * NU);
            ldrow<NU>(u2, G + (size_t)s2 * ROWU + lane * NU);
            ldrow<NU>(u3, G + (size_t)s3 * ROWU + lane * NU);
            const float n0 = csr_norm[e],     n1 = csr_norm[e + 1];
            const float n2 = csr_norm[e + 2], n3 = csr_norm[e + 3];
            acc_row<NU>(a, u0, n0);
            acc_row<NU>(a, u1, n1);
            acc_row<NU>(a, u2, n2);
            acc_row<NU>(a, u3, n3);
        }
        for (; e < end; ++e) {
            const int s = csr_src[e];
            unsigned u[NU];
            ldrow<NU>(u, G + (size_t)s * ROWU + lane * NU);
            acc_row<NU>(a, u, csr_norm[e]);
        }
        const int row = w * 16 + j * 4 + (lane >> 4);
        unsigned p[NU];
#pragma unroll
        for (int c = 0; c < NU; ++c) p[c] = pack2(a[2 * c], a[2 * c + 1]);
        if constexpr (NU == 2) *(uint2*)&sA[row * AST + cg * 4] = *(const uint2*)p;
        else                   *(uint4*)&sA[row * AST + cg * 8] = *(const uint4*)p;
    }
    __syncthreads();

    // MFMA: wave w owns rows w*16..+15
    const int rowL = w * 16 + (lane & 15);
    const int kg = lane >> 4;
    f32x4 acc[8];
#pragma unroll
    for (int t = 0; t < 8; ++t) acc[t] = (f32x4){0.f, 0.f, 0.f, 0.f};
#pragma unroll
    for (int ks = 0; ks < NKS; ++ks) {
        const bf16x8 av = *(const bf16x8*)&sA[rowL * AST + ks * 32 + kg * 8];
#pragma unroll
        for (int t = 0; t < 8; ++t) {
            const bf16x8 bv = *(const bf16x8*)&sB[((t * NKS + ks) * 64 + lane) * 8];
            acc[t] = __builtin_amdgcn_mfma_f32_16x16x32_bf16(av, bv, acc[t], 0, 0, 0);
        }
    }

    // epilogue: +bias (+ns*shW2 for L2E), ReLU, bf16 store, BN partial stats
    const int colb = lane & 15;
    const int rbase = w * 16 + kg * 4;        // 4 regs = 4 batches of ONE node
    float ns = 0.f;
    if (L2E) ns = nsum[(row0 + rbase) >> 2];
#pragma unroll
    for (int t = 0; t < 8; ++t) {
        const int col = t * 16 + colb;
        float badd = bias[col];
        if (L2E) badd = fmaf(ns, shW2[col], badd);
        float s = 0.f, q = 0.f;
#pragma unroll
        for (int j = 0; j < 4; ++j) {
            const float y = fmaxf(acc[t][j] + badd, 0.f);
            const size_t r = (size_t)(row0 + rbase + j);
            Yout[r * 128 + col] = (unsigned short)f2bf(y);
            s += y; q = fmaf(y, y, q);
        }
        atomicAdd(&lsum[col], s);
        atomicAdd(&lsq[col], q);
    }
    __syncthreads();
    float* gs = gsum + (size_t)(blockIdx.x & (NSLOTS - 1)) * 128;
    float* gq = gsq  + (size_t)(blockIdx.x & (NSLOTS - 1)) * 128;
    if (tid < 128) { atomicAdd(&gs[tid], lsum[tid]); atomicAdd(&gq[tid], lsq[tid]); }
}

// ---------------------------------------------------------------------------
// K8: BN2 finalize folded into classifier weights:
//   wcs[c] = sc2[c]*Wc[c],  kc = sum_c sh2[c]*Wc[c] + bc
__global__ void k_bnfin2(const float* __restrict__ gsum, const float* __restrict__ gsq,
                         const float* __restrict__ gamma, const float* __restrict__ beta,
                         const float* __restrict__ Wc, const float* __restrict__ bc,
                         float* __restrict__ wcs, float* __restrict__ kc) {
    __shared__ float red[128];
    const int c = threadIdx.x;
    float s = 0.f, q = 0.f;
    for (int j = 0; j < NSLOTS; ++j) { s += gsum[j * 128 + c]; q += gsq[j * 128 + c]; }
    const float inv = 1.0f / (float)(Bb * Nn);
    const float mu  = s * inv;
    const float var = q * inv - mu * mu;
    const float sc  = gamma[c] * rsqrtf(var + BN_EPS);
    const float sh  = beta[c] - mu * sc;
    const float w   = Wc[c];
    wcs[c] = sc * w;
    red[c] = sh * w;
    __syncthreads();
    for (int st = 64; st; st >>= 1) {
        if (c < st) red[c] += red[c + st];
        __syncthreads();
    }
    if (c == 0) kc[0] = red[0] + bc[0];
}

// ---------------------------------------------------------------------------
// K9: classifier on bf16 h2: out[b*Nn+n] = sum_c h2[r][c]*wcs[c] + kc
__global__ __launch_bounds__(256) void k_cls(const unsigned* __restrict__ h2,
                                             const float* __restrict__ wcs,
                                             const float* __restrict__ kc,
                                             float* __restrict__ out) {
    const int wave = threadIdx.x >> 6;
    const int lane = threadIdx.x & 63;
    const size_t row = (size_t)blockIdx.x * 4 + wave;
    if (row >= (size_t)Bb * Nn) return;
    const unsigned w = h2[row * 64 + lane];          // 2 channels
    const float2 wc = *(const float2*)&wcs[lane * 2];
    float p = bf_lo(w) * wc.x + bf_hi(w) * wc.y;
#pragma unroll
    for (int off = 32; off; off >>= 1) p += __shfl_down(p, off);
    if (lane == 0) {
        const int n = (int)(row >> 2), b = (int)(row & 3);
        out[(size_t)b * Nn + n] = p + kc[0];
    }
}

// ---------------------------------------------------------------------------
extern "C" void kernel_launch(void* const* d_in, const int* in_sizes, int n_in,
                              void* d_out, int out_size, void* d_ws, size_t ws_size,
                              hipStream_t stream) {
    const float* x      = (const float*)d_in[0];
    const int*   ei     = (const int*)d_in[1];
    const float* W1     = (const float*)d_in[2];
    const float* b1     = (const float*)d_in[3];
    const float* W2     = (const float*)d_in[4];
    const float* b2     = (const float*)d_in[5];
    const float* gamma1 = (const float*)d_in[6];
    const float* beta1  = (const float*)d_in[7];
    const float* gamma2 = (const float*)d_in[8];
    const float* beta2  = (const float*)d_in[9];
    const float* Wc     = (const float*)d_in[10];
    const float* bc     = (const float*)d_in[11];
    float* out = (float*)d_out;

    const int E = in_sizes[1] / 2;
    const int* src = ei;
    const int* dst = ei + E;

    char* ws = (char*)d_ws;
    size_t off = 0;
    auto alloc = [&](size_t bytes) -> char* {
        char* p = ws + off;
        off += (bytes + 255) & ~(size_t)255;
        return p;
    };
    // zero-init region: deg, nsum, gstat contiguous -> ONE memset
    int*      deg      = (int*)     alloc((size_t)Nn * 4);
    float*    nsum     = (float*)   alloc((size_t)Nn * 4);
    float*    gstat    = (float*)   alloc((size_t)4 * NSLOTS * 128 * 4);
    const size_t zspan = (size_t)((char*)(gstat + 4 * NSLOTS * 128) - (char*)deg);
    float* gsum1 = gstat;
    float* gsq1  = gstat + NSLOTS * 128;
    float* gsum2 = gstat + 2 * NSLOTS * 128;
    float* gsq2  = gstat + 3 * NSLOTS * 128;

    int*      cursor   = (int*)     alloc((size_t)Nn * 4);
    int*      rowptr   = (int*)     alloc((size_t)(Nn + 1) * 4);
    int*      bsum     = (int*)     alloc((size_t)NB * 4);
    float*    dinv     = (float*)   alloc((size_t)Nn * 4);
    int*      csr_src  = (int*)     alloc((size_t)(E + Nn) * 4);
    float*    csr_norm = (float*)   alloc((size_t)(E + Nn) * 4);
    float*    wcs      = (float*)   alloc(128 * 4);
    float*    kc       = (float*)   alloc(256);
    unsigned short* WT1  = (unsigned short*)alloc((size_t)128 * Ff * 2);
    unsigned short* WT2  = (unsigned short*)alloc((size_t)128 * Hh * 2);
    float*          shW2 = (float*)         alloc((size_t)128 * 4);
    unsigned*       xb   = (unsigned*)      alloc((size_t)Nn * Bb * 32 * 4);  // bf16 x node-major
    unsigned short* h1b  = (unsigned short*)alloc((size_t)Bb * Nn * Hh * 2);  // bf16 [80000][128]
    unsigned short* h2b  = (unsigned short*)alloc((size_t)Bb * Nn * Hh * 2);  // bf16 [80000][128]

    (void)hipMemsetAsync(deg, 0, zspan, stream);

    k_deg<<<(E + 255) / 256, 256, 0, stream>>>(dst, E, deg);
    k_scan1<<<NB, 1024, 0, stream>>>(deg, rowptr, bsum);
    k_scan2<<<1, 64, 0, stream>>>(bsum);
    k_scan3<<<NB, 1024, 0, stream>>>(deg, rowptr, bsum, cursor, dinv);
    k_fill<<<(E + Nn + 255) / 256, 256, 0, stream>>>(src, dst, E, dinv, cursor,
                                                     csr_src, csr_norm, nsum);
    k_cvt<<<(Bb * Nn * 32 + 255) / 256, 256, 0, stream>>>(x, xb);
    k_wt1<<<(128 * Ff) / 256, 256, 0, stream>>>(W1, WT1);

    // Layer 1: fused agg(x)@W1 (+b1, ReLU, BN1 stats, bf16 out)
    k_fmm<Ff, false><<<Nn / 16, 256, 0, stream>>>(
        xb, rowptr, csr_src, csr_norm, WT1, b1, nullptr, nullptr, h1b, gsum1, gsq1);
    // BN1 finalize + fold into WT2/shW2
    k_prep2<<<65, 128, 0, stream>>>(gsum1, gsq1, gamma1, beta1, W2, WT2, shW2);
    // Layer 2: fused agg(h1)@(sc1.W2) + nsum*(sh1@W2) + b2, ReLU, BN2 stats
    k_fmm<Hh, true><<<Nn / 16, 256, 0, stream>>>(
        (const unsigned*)h1b, rowptr, csr_src, csr_norm, WT2, b2, nsum, shW2,
        h2b, gsum2, gsq2);
    k_bnfin2<<<1, Hh, 0, stream>>>(gsum2, gsq2, gamma2, beta2, Wc, bc, wcs, kc);

    // Classifier (BN2 folded into wcs/kc)
    k_cls<<<(Bb * Nn + 3) / 4, 256, 0, stream>>>((const unsigned*)h2b, wcs, kc, out);
}